// Round 6
// baseline (384.508 us; speedup 1.0000x reference)
//
#include <hip/hip_runtime.h>
#include <hip/hip_bf16.h>
#include <stdint.h>

// Fused causal self-attention block: qkv GEMM -> flash attention -> proj GEMM.
// B=4 T=2048 E=1024 H=16 HD=64. All GEMM/attn matmuls in bf16 MFMA
// (mfma_f32_16x16x32_bf16), fp32 accumulate.

#define B_  4
#define T_  2048
#define E_  1024
#define H_  16
#define HD_ 64

typedef unsigned short u16;
typedef __bf16 bf16x8 __attribute__((ext_vector_type(8)));
typedef float f32x4 __attribute__((ext_vector_type(4)));

struct alignas(8) us4 { u16 x, y, z, w; };

// native bf16 convert (compiler emits v_cvt_pk_bf16_f32; RNE)
__device__ __forceinline__ u16 tobf(float f) {
  union { __bf16 h; u16 u; } c;
  c.h = (__bf16)f;
  return c.u;
}

__device__ __forceinline__ void gload_lds16(const void* g, void* l) {
  // global -> LDS direct, 16B per lane (wave-uniform LDS base + lane*16).
  auto gp = reinterpret_cast<const __attribute__((address_space(1))) uint32_t*>(
      reinterpret_cast<uintptr_t>(g));
  auto lp = reinterpret_cast<__attribute__((address_space(3))) uint32_t*>(
      reinterpret_cast<uintptr_t>(l));
  __builtin_amdgcn_global_load_lds(gp, lp, 16, 0, 0);
}

__device__ __forceinline__ bf16x8 ld_frag(const u16* p) {
  return *reinterpret_cast<const bf16x8*>(p);
}

// DPP-based 16-lane all-reduce (pure VALU: quad_perm xor1, xor2, row_ror 4, 8)
#define DPPF(x, ctrl) __uint_as_float((unsigned)__builtin_amdgcn_update_dpp( \
    (int)__float_as_uint(x), (int)__float_as_uint(x), (ctrl), 0xF, 0xF, true))

__device__ __forceinline__ float rmax16(float x) {
  x = fmaxf(x, DPPF(x, 0xB1));   // quad_perm xor1
  x = fmaxf(x, DPPF(x, 0x4E));   // quad_perm xor2
  x = fmaxf(x, DPPF(x, 0x124));  // row_ror:4
  x = fmaxf(x, DPPF(x, 0x128));  // row_ror:8
  return x;
}
__device__ __forceinline__ float rsum16(float x) {
  x += DPPF(x, 0xB1);
  x += DPPF(x, 0x4E);
  x += DPPF(x, 0x124);
  x += DPPF(x, 0x128);
  return x;
}

// ---------------- conversion kernels ----------------

__global__ void cvt_bf16_kernel(const float* __restrict__ in, u16* __restrict__ out, int n) {
  int i = (blockIdx.x * blockDim.x + threadIdx.x) * 4;
  if (i >= n) return;
  float4 v = *reinterpret_cast<const float4*>(in + i);
  us4 o = { tobf(v.x), tobf(v.y), tobf(v.z), tobf(v.w) };
  *reinterpret_cast<us4*>(out + i) = o;
}

// in: [K][N] f32 row-major -> out: [N][K] bf16 (B^T layout for GEMM)
__global__ void transpose_cvt_kernel(const float* __restrict__ in, u16* __restrict__ out,
                                     int K, int N) {
  __shared__ u16 tile[32][33];
  int n0 = blockIdx.x * 32, k0 = blockIdx.y * 32;
  int tx = threadIdx.x, ty = threadIdx.y;  // (32,8)
#pragma unroll
  for (int i = 0; i < 32; i += 8)
    tile[ty + i][tx] = tobf(in[(size_t)(k0 + ty + i) * N + n0 + tx]);
  __syncthreads();
#pragma unroll
  for (int i = 0; i < 32; i += 8)
    out[(size_t)(n0 + ty + i) * K + k0 + tx] = tile[tx][ty + i];
}

// ---------------- GEMM (m97-style 128x128 tile, BK=32) ----------------

template <int MODE>
__launch_bounds__(256)
__global__ void gemm_kernel(const u16* __restrict__ A, const u16* __restrict__ Bt,
                            const float* __restrict__ bias,
                            u16* __restrict__ qws, u16* __restrict__ kws,
                            u16* __restrict__ vtws, float* __restrict__ out) {
  constexpr int K = 1024, BK = 32;
  __shared__ u16 As[128 * BK];
  __shared__ u16 Bs[128 * BK];
  const int tid = threadIdx.x;
  const int wid = tid >> 6, lane = tid & 63;
  const int wm = wid >> 1, wn = wid & 1;  // 2x2 wave grid, 64x64 per wave
  const int row0 = blockIdx.x * 128, col0 = blockIdx.y * 128;

  f32x4 acc[4][4] = {};

  const int sr = lane >> 2;
  const int sc = (lane & 3) * 8;
  const int lrow = lane & 15;
  const int lkb = (lane >> 4) * 8;

  for (int k0 = 0; k0 < K; k0 += BK) {
#pragma unroll
    for (int c = 0; c < 2; ++c) {
      int chunk = wid * 2 + c;
      int r = chunk * 16 + sr;
      gload_lds16(A + (size_t)(row0 + r) * K + k0 + sc, &As[chunk * 512]);
      gload_lds16(Bt + (size_t)(col0 + r) * K + k0 + sc, &Bs[chunk * 512]);
    }
    __syncthreads();
    bf16x8 af[4], bf[4];
#pragma unroll
    for (int i = 0; i < 4; ++i) {
      af[i] = ld_frag(&As[(wm * 64 + i * 16 + lrow) * BK + lkb]);
      bf[i] = ld_frag(&Bs[(wn * 64 + i * 16 + lrow) * BK + lkb]);
    }
#pragma unroll
    for (int i = 0; i < 4; ++i)
#pragma unroll
      for (int j = 0; j < 4; ++j)
        acc[i][j] = __builtin_amdgcn_mfma_f32_16x16x32_bf16(af[i], bf[j], acc[i][j], 0, 0, 0);
    __syncthreads();
  }

  // C/D layout: col = lane&15, row = (lane>>4)*4 + reg
#pragma unroll
  for (int mi = 0; mi < 4; ++mi) {
#pragma unroll
    for (int ni = 0; ni < 4; ++ni) {
      const int gr0 = row0 + wm * 64 + mi * 16 + (lane >> 4) * 4;
      const int gc = col0 + wn * 64 + ni * 16 + (lane & 15);
      const float bv = bias[gc];
      f32x4 v = acc[mi][ni];
      if constexpr (MODE == 0) {
        const int part = gc >> 10;          // 0=q 1=k 2=v
        const int e = gc & 1023;
        const int h = e >> 6, d = e & 63;
#pragma unroll
        for (int r = 0; r < 4; ++r) {
          const int m = gr0 + r;
          const int b = m >> 11, t = m & 2047;
          const float val = v[r] + bv;
          const size_t bh = (size_t)(b * H_ + h);
          if (part == 0)
            // fold 1/sqrt(64) * log2(e): softmax done in exp2 domain
            qws[(bh * T_ + t) * HD_ + d] = tobf(val * 0.1803368801f);
          else if (part == 1)
            kws[(bh * T_ + t) * HD_ + d] = tobf(val);
          else
            vtws[(bh * HD_ + d) * T_ + t] = tobf(val);          // V transposed
        }
      } else {
#pragma unroll
        for (int r = 0; r < 4; ++r) {
          const int m = gr0 + r;
          out[(size_t)m * E_ + gc] = v[r] + bv;
        }
      }
    }
  }
}

// ---------------- flash attention (shared-KV LDS, 8 waves) ----------------
// grid = 512 blocks x 512 threads = 2 blocks/CU (16 waves/CU, 4/SIMD).
// Block bid<256: head bh=bid>>2, Q-tile j=bid&3; bid>=256: same bh, j=7-(bid&3).
// Under round-robin dispatch CU c gets bids {c, c+256}: same head (K/V L2
// reuse) and complementary j (constant per-CU work). Wave w owns 32 Q rows
// (Q + O in registers). Per KV-64 step: K tile [64kv][64hd] and V^T tile
// [64d][64kv] staged to LDS (double-buffered, global_load_lds w16). LDS tiles
// XOR-swizzled (slot ^= row&7, 16B slots, T21). Softmax in exp2 domain with
// T13 defer-max; T5 setprio around MFMA clusters.

__launch_bounds__(512, 4)
__global__ void attn_kernel(const u16* __restrict__ q, const u16* __restrict__ k,
                            const u16* __restrict__ vt, u16* __restrict__ y) {
  __shared__ u16 kl[2][64 * 64];   // [buf][kvrow][hd] swizzled
  __shared__ u16 vl[2][64 * 64];   // [buf][d][kv] swizzled
  __shared__ u16 pt[8][32][72];    // per-wave P tile (padded)
  const int tid = threadIdx.x, w = tid >> 6, lane = tid & 63;
  const int bid = blockIdx.x;
  const int rb = bid & 255;
  const int bh = rb >> 2;
  const int jj = rb & 3;
  const int j = (bid >> 8) ? (7 - jj) : jj;   // complementary pairing
  const u16* qp = q + (size_t)bh * T_ * HD_;
  const u16* kp = k + (size_t)bh * T_ * HD_;
  const u16* vp = vt + (size_t)bh * HD_ * T_;
  const int b = bh >> 4, h = bh & 15;
  u16* yb = y + (size_t)b * T_ * E_ + h * HD_;
  u16* ptw = &pt[w][0][0];
  const int lc = lane & 15, lk = lane >> 4;
  const int srow = lane >> 3;      // 0..7: row within this wave's 8-row group
  const int sslot = lane & 7;      // 16B slot within 128B row
  const int sco = ((sslot ^ srow) * 8);  // inverse-swizzled source elem offset
  const int rdm = (lc & 7) * 8;    // read-side XOR mask (elems)

  const int t0 = j * 256;
  const int qb = t0 + w * 32;              // this wave's first Q row
  const int nblk = (t0 + 256) >> 6;        // KV blocks to process

  bf16x8 aq[2][2];
#pragma unroll
  for (int m = 0; m < 2; ++m)
#pragma unroll
    for (int sl = 0; sl < 2; ++sl)
      aq[m][sl] = ld_frag(qp + (size_t)(qb + m * 16 + lc) * HD_ + sl * 32 + lk * 8);

  f32x4 o[2][4] = {};
  float mr[2][4], lr[2][4];
#pragma unroll
  for (int m = 0; m < 2; ++m)
#pragma unroll
    for (int r = 0; r < 4; ++r) { mr[m][r] = -1e30f; lr[m][r] = 0.f; }

  // prologue: stage KV block 0 into buf 0
  gload_lds16(kp + (size_t)(8 * w + srow) * HD_ + sco, &kl[0][w * 512]);
  gload_lds16(vp + (size_t)(8 * w + srow) * T_ + sco, &vl[0][w * 512]);
  __syncthreads();

  int buf = 0;
  for (int kb = 0; kb < nblk; ++kb) {
    const int kv0 = kb * 64;
    if (kb + 1 < nblk) {  // stage next block into other buffer
      const int kvn = kv0 + 64;
      gload_lds16(kp + (size_t)(kvn + 8 * w + srow) * HD_ + sco, &kl[buf ^ 1][w * 512]);
      gload_lds16(vp + (size_t)(8 * w + srow) * T_ + kvn + sco, &vl[buf ^ 1][w * 512]);
    }
    if (kv0 < qb + 32) {  // wave-uniform causal skip
      // K frags from LDS (swizzled read)
      bf16x8 kf[4][2];
#pragma unroll
      for (int n = 0; n < 4; ++n)
#pragma unroll
        for (int sl = 0; sl < 2; ++sl)
          kf[n][sl] = ld_frag(&kl[buf][(n * 16 + lc) * 64 + ((sl * 32 + lk * 8) ^ rdm)]);
      // S = Q K^T : 32 q-rows x 64 kv
      f32x4 s[2][4] = {};
      __builtin_amdgcn_s_setprio(1);
#pragma unroll
      for (int m = 0; m < 2; ++m)
#pragma unroll
        for (int n = 0; n < 4; ++n) {
          s[m][n] = __builtin_amdgcn_mfma_f32_16x16x32_bf16(aq[m][0], kf[n][0], s[m][n], 0, 0, 0);
          s[m][n] = __builtin_amdgcn_mfma_f32_16x16x32_bf16(aq[m][1], kf[n][1], s[m][n], 0, 0, 0);
        }
      __builtin_amdgcn_s_setprio(0);
      // V frags (issue early; consumed by PV)
      bf16x8 vf[4][2];
#pragma unroll
      for (int n = 0; n < 4; ++n)
#pragma unroll
        for (int ks = 0; ks < 2; ++ks)
          vf[n][ks] = ld_frag(&vl[buf][(n * 16 + lc) * 64 + ((ks * 32 + lk * 8) ^ rdm)]);
      // causal mask
      if (kv0 + 63 > qb) {
#pragma unroll
        for (int m = 0; m < 2; ++m)
#pragma unroll
          for (int n = 0; n < 4; ++n) {
            const int kv = kv0 + n * 16 + lc;
#pragma unroll
            for (int r = 0; r < 4; ++r)
              if (kv > qb + m * 16 + lk * 4 + r) s[m][n][r] = -1e30f;
          }
      }
      // online softmax (exp2 domain) with deferred rescale (T13)
      float pm[2][4];
      int need = 0;
#pragma unroll
      for (int m = 0; m < 2; ++m)
#pragma unroll
        for (int r = 0; r < 4; ++r) {
          float v = fmaxf(fmaxf(s[m][0][r], s[m][1][r]), fmaxf(s[m][2][r], s[m][3][r]));
          v = rmax16(v);
          pm[m][r] = v;
          need |= (v - mr[m][r] > 8.f) ? 1 : 0;
        }
      if (__any(need)) {
        float al[2][4];
#pragma unroll
        for (int m = 0; m < 2; ++m)
#pragma unroll
          for (int r = 0; r < 4; ++r) {
            const float mn = fmaxf(mr[m][r], pm[m][r]);
            al[m][r] = exp2f(mr[m][r] - mn);
            mr[m][r] = mn;
            lr[m][r] *= al[m][r];
          }
#pragma unroll
        for (int m = 0; m < 2; ++m)
#pragma unroll
          for (int n = 0; n < 4; ++n)
#pragma unroll
            for (int r = 0; r < 4; ++r)
              o[m][n][r] *= al[m][r];
      }
      float rs[2][4] = {};
#pragma unroll
      for (int m = 0; m < 2; ++m)
#pragma unroll
        for (int n = 0; n < 4; ++n)
#pragma unroll
          for (int r = 0; r < 4; ++r) {
            const float p = exp2f(s[m][n][r] - mr[m][r]);
            s[m][n][r] = p;
            rs[m][r] += p;
          }
#pragma unroll
      for (int m = 0; m < 2; ++m)
#pragma unroll
        for (int r = 0; r < 4; ++r)
          lr[m][r] += rsum16(rs[m][r]);
      // P (C-layout) -> LDS -> A-layout frags (per-wave region, no barrier)
#pragma unroll
      for (int m = 0; m < 2; ++m)
#pragma unroll
        for (int n = 0; n < 4; ++n)
#pragma unroll
          for (int r = 0; r < 4; ++r)
            pt[w][m * 16 + lk * 4 + r][n * 16 + lc] = tobf(s[m][n][r]);
      bf16x8 pa[2][2];
#pragma unroll
      for (int m = 0; m < 2; ++m)
#pragma unroll
        for (int ks = 0; ks < 2; ++ks)
          pa[m][ks] = ld_frag(&ptw[(m * 16 + lc) * 72 + ks * 32 + lk * 8]);
      // O += P V
      __builtin_amdgcn_s_setprio(1);
#pragma unroll
      for (int m = 0; m < 2; ++m)
#pragma unroll
        for (int n = 0; n < 4; ++n) {
          o[m][n] = __builtin_amdgcn_mfma_f32_16x16x32_bf16(pa[m][0], vf[n][0], o[m][n], 0, 0, 0);
          o[m][n] = __builtin_amdgcn_mfma_f32_16x16x32_bf16(pa[m][1], vf[n][1], o[m][n], 0, 0, 0);
        }
      __builtin_amdgcn_s_setprio(0);
    }
    __syncthreads();
    buf ^= 1;
  }

  float invl[2][4];
#pragma unroll
  for (int m = 0; m < 2; ++m)
#pragma unroll
    for (int r = 0; r < 4; ++r) invl[m][r] = 1.f / lr[m][r];
#pragma unroll
  for (int m = 0; m < 2; ++m)
#pragma unroll
    for (int n = 0; n < 4; ++n)
#pragma unroll
      for (int r = 0; r < 4; ++r) {
        const int t = qb + m * 16 + lk * 4 + r;
        yb[(size_t)t * E_ + n * 16 + lc] = tobf(o[m][n][r] * invl[m][r]);
      }
}

// ---------------- launch ----------------

extern "C" void kernel_launch(void* const* d_in, const int* in_sizes, int n_in,
                              void* d_out, int out_size, void* d_ws, size_t ws_size,
                              hipStream_t stream) {
  const float* x  = (const float*)d_in[0];
  const float* Wa = (const float*)d_in[1];
  const float* ba = (const float*)d_in[2];
  const float* Wp = (const float*)d_in[3];
  const float* bp = (const float*)d_in[4];
  float* out = (float*)d_out;

  u16* ws   = (u16*)d_ws;
  u16* xb   = ws;                                  // 8M  (x bf16; later y bf16)
  u16* waT  = xb  + (size_t)8 * 1024 * 1024;       // 3M  (W_attn^T bf16)
  u16* wpT  = waT + (size_t)3 * 1024 * 1024;       // 1M  (W_proj^T bf16)
  u16* qws  = wpT + (size_t)1024 * 1024;           // 8M  q [B,H,T,HD]
  u16* kws  = qws + (size_t)8 * 1024 * 1024;       // 8M  k [B,H,T,HD]
  u16* vtws = kws + (size_t)8 * 1024 * 1024;       // 8M  v^T [B,H,HD,T]
  u16* yws  = xb;                                  // alias

  cvt_bf16_kernel<<<dim3(8192), dim3(256), 0, stream>>>(x, xb, 8 * 1024 * 1024);
  transpose_cvt_kernel<<<dim3(96, 32), dim3(32, 8), 0, stream>>>(Wa, waT, 1024, 3072);
  transpose_cvt_kernel<<<dim3(32, 32), dim3(32, 8), 0, stream>>>(Wp, wpT, 1024, 1024);

  gemm_kernel<0><<<dim3(64, 24), dim3(256), 0, stream>>>(xb, waT, ba, qws, kws, vtws, nullptr);
  attn_kernel<<<dim3(512), dim3(512), 0, stream>>>(qws, kws, vtws, yws);
  gemm_kernel<1><<<dim3(64, 8), dim3(256), 0, stream>>>(yws, wpT, bp, nullptr, nullptr, nullptr, out);
}

// Round 7
// 226.570 us; speedup vs baseline: 1.6971x; 1.6971x over previous
//
#include <hip/hip_runtime.h>
#include <hip/hip_bf16.h>
#include <stdint.h>

// Fused causal self-attention block: qkv GEMM -> flash attention -> proj GEMM.
// B=4 T=2048 E=1024 H=16 HD=64. All GEMM/attn matmuls in bf16 MFMA
// (mfma_f32_16x16x32_bf16), fp32 accumulate.

#define B_  4
#define T_  2048
#define E_  1024
#define H_  16
#define HD_ 64

typedef unsigned short u16;
typedef __bf16 bf16x8 __attribute__((ext_vector_type(8)));
typedef float f32x4 __attribute__((ext_vector_type(4)));

struct alignas(8) us4 { u16 x, y, z, w; };

// native bf16 convert (compiler emits v_cvt_pk_bf16_f32; RNE)
__device__ __forceinline__ u16 tobf(float f) {
  union { __bf16 h; u16 u; } c;
  c.h = (__bf16)f;
  return c.u;
}

__device__ __forceinline__ void gload_lds16(const void* g, void* l) {
  // global -> LDS direct, 16B per lane (wave-uniform LDS base + lane*16).
  auto gp = reinterpret_cast<const __attribute__((address_space(1))) uint32_t*>(
      reinterpret_cast<uintptr_t>(g));
  auto lp = reinterpret_cast<__attribute__((address_space(3))) uint32_t*>(
      reinterpret_cast<uintptr_t>(l));
  __builtin_amdgcn_global_load_lds(gp, lp, 16, 0, 0);
}

__device__ __forceinline__ bf16x8 ld_frag(const u16* p) {
  return *reinterpret_cast<const bf16x8*>(p);
}

// DPP-based 16-lane all-reduce (pure VALU: quad_perm xor1, xor2, row_ror 4, 8)
#define DPPF(x, ctrl) __uint_as_float((unsigned)__builtin_amdgcn_update_dpp( \
    (int)__float_as_uint(x), (int)__float_as_uint(x), (ctrl), 0xF, 0xF, true))

__device__ __forceinline__ float rmax16(float x) {
  x = fmaxf(x, DPPF(x, 0xB1));   // quad_perm xor1
  x = fmaxf(x, DPPF(x, 0x4E));   // quad_perm xor2
  x = fmaxf(x, DPPF(x, 0x124));  // row_ror:4
  x = fmaxf(x, DPPF(x, 0x128));  // row_ror:8
  return x;
}
__device__ __forceinline__ float rsum16(float x) {
  x += DPPF(x, 0xB1);
  x += DPPF(x, 0x4E);
  x += DPPF(x, 0x124);
  x += DPPF(x, 0x128);
  return x;
}

// ---------------- conversion kernels ----------------

__global__ void cvt_bf16_kernel(const float* __restrict__ in, u16* __restrict__ out, int n) {
  int i = (blockIdx.x * blockDim.x + threadIdx.x) * 4;
  if (i >= n) return;
  float4 v = *reinterpret_cast<const float4*>(in + i);
  us4 o = { tobf(v.x), tobf(v.y), tobf(v.z), tobf(v.w) };
  *reinterpret_cast<us4*>(out + i) = o;
}

// in: [K][N] f32 row-major -> out: [N][K] bf16 (B^T layout for GEMM)
__global__ void transpose_cvt_kernel(const float* __restrict__ in, u16* __restrict__ out,
                                     int K, int N) {
  __shared__ u16 tile[32][33];
  int n0 = blockIdx.x * 32, k0 = blockIdx.y * 32;
  int tx = threadIdx.x, ty = threadIdx.y;  // (32,8)
#pragma unroll
  for (int i = 0; i < 32; i += 8)
    tile[ty + i][tx] = tobf(in[(size_t)(k0 + ty + i) * N + n0 + tx]);
  __syncthreads();
#pragma unroll
  for (int i = 0; i < 32; i += 8)
    out[(size_t)(n0 + ty + i) * K + k0 + tx] = tile[tx][ty + i];
}

// ---------------- GEMM (m97-style 128x128 tile, BK=32) ----------------

template <int MODE>
__launch_bounds__(256)
__global__ void gemm_kernel(const u16* __restrict__ A, const u16* __restrict__ Bt,
                            const float* __restrict__ bias,
                            u16* __restrict__ qws, u16* __restrict__ kws,
                            u16* __restrict__ vtws, float* __restrict__ out) {
  constexpr int K = 1024, BK = 32;
  __shared__ u16 As[128 * BK];
  __shared__ u16 Bs[128 * BK];
  const int tid = threadIdx.x;
  const int wid = tid >> 6, lane = tid & 63;
  const int wm = wid >> 1, wn = wid & 1;  // 2x2 wave grid, 64x64 per wave
  const int row0 = blockIdx.x * 128, col0 = blockIdx.y * 128;

  f32x4 acc[4][4] = {};

  const int sr = lane >> 2;
  const int sc = (lane & 3) * 8;
  const int lrow = lane & 15;
  const int lkb = (lane >> 4) * 8;

  for (int k0 = 0; k0 < K; k0 += BK) {
#pragma unroll
    for (int c = 0; c < 2; ++c) {
      int chunk = wid * 2 + c;
      int r = chunk * 16 + sr;
      gload_lds16(A + (size_t)(row0 + r) * K + k0 + sc, &As[chunk * 512]);
      gload_lds16(Bt + (size_t)(col0 + r) * K + k0 + sc, &Bs[chunk * 512]);
    }
    __syncthreads();
    bf16x8 af[4], bf[4];
#pragma unroll
    for (int i = 0; i < 4; ++i) {
      af[i] = ld_frag(&As[(wm * 64 + i * 16 + lrow) * BK + lkb]);
      bf[i] = ld_frag(&Bs[(wn * 64 + i * 16 + lrow) * BK + lkb]);
    }
#pragma unroll
    for (int i = 0; i < 4; ++i)
#pragma unroll
      for (int j = 0; j < 4; ++j)
        acc[i][j] = __builtin_amdgcn_mfma_f32_16x16x32_bf16(af[i], bf[j], acc[i][j], 0, 0, 0);
    __syncthreads();
  }

  // C/D layout: col = lane&15, row = (lane>>4)*4 + reg
#pragma unroll
  for (int mi = 0; mi < 4; ++mi) {
#pragma unroll
    for (int ni = 0; ni < 4; ++ni) {
      const int gr0 = row0 + wm * 64 + mi * 16 + (lane >> 4) * 4;
      const int gc = col0 + wn * 64 + ni * 16 + (lane & 15);
      const float bv = bias[gc];
      f32x4 v = acc[mi][ni];
      if constexpr (MODE == 0) {
        const int part = gc >> 10;          // 0=q 1=k 2=v
        const int e = gc & 1023;
        const int h = e >> 6, d = e & 63;
#pragma unroll
        for (int r = 0; r < 4; ++r) {
          const int m = gr0 + r;
          const int b = m >> 11, t = m & 2047;
          const float val = v[r] + bv;
          const size_t bh = (size_t)(b * H_ + h);
          if (part == 0)
            // fold 1/sqrt(64) * log2(e): softmax done in exp2 domain
            qws[(bh * T_ + t) * HD_ + d] = tobf(val * 0.1803368801f);
          else if (part == 1)
            kws[(bh * T_ + t) * HD_ + d] = tobf(val);
          else
            vtws[(bh * HD_ + d) * T_ + t] = tobf(val);          // V transposed
        }
      } else {
#pragma unroll
        for (int r = 0; r < 4; ++r) {
          const int m = gr0 + r;
          out[(size_t)m * E_ + gc] = v[r] + bv;
        }
      }
    }
  }
}

// ---------------- flash attention (shared-KV LDS, 8 waves) ----------------
// grid = 512 blocks x 512 threads; 2 blocks/CU co-resident (limited by LDS:
// 69.6KB each, 139KB/CU of 160KB). Block bid<256: head bh=bid>>2, Q-tile
// j=bid&3; bid>=256: same bh, j=7-(bid&3) -> CU c gets {c, c+256}: same head
// (K/V L2 reuse), complementary work. launch_bounds (512,2): do NOT request
// more waves -- (512,4) capped VGPR at 64 and spilled 560MB to scratch (R6).
// Wave w owns 32 Q rows (Q + O in registers). Per KV-64 step: K tile
// [64kv][64hd] and V^T tile [64d][64kv] staged to LDS (double-buffered,
// global_load_lds w16). LDS XOR-swizzled (slot ^= row&7, 16B slots, T21).
// Softmax in exp2 domain with T13 defer-max; T5 setprio around MFMA.

__launch_bounds__(512, 2)
__global__ void attn_kernel(const u16* __restrict__ q, const u16* __restrict__ k,
                            const u16* __restrict__ vt, u16* __restrict__ y) {
  __shared__ u16 kl[2][64 * 64];   // [buf][kvrow][hd] swizzled
  __shared__ u16 vl[2][64 * 64];   // [buf][d][kv] swizzled
  __shared__ u16 pt[8][32][72];    // per-wave P tile (padded)
  const int tid = threadIdx.x, w = tid >> 6, lane = tid & 63;
  const int bid = blockIdx.x;
  const int rb = bid & 255;
  const int bh = rb >> 2;
  const int jj = rb & 3;
  const int j = (bid >> 8) ? (7 - jj) : jj;   // complementary pairing
  const u16* qp = q + (size_t)bh * T_ * HD_;
  const u16* kp = k + (size_t)bh * T_ * HD_;
  const u16* vp = vt + (size_t)bh * HD_ * T_;
  const int b = bh >> 4, h = bh & 15;
  u16* yb = y + (size_t)b * T_ * E_ + h * HD_;
  u16* ptw = &pt[w][0][0];
  const int lc = lane & 15, lk = lane >> 4;
  const int srow = lane >> 3;      // 0..7: row within this wave's 8-row group
  const int sslot = lane & 7;      // 16B slot within 128B row
  const int sco = ((sslot ^ srow) * 8);  // inverse-swizzled source elem offset
  const int rdm = (lc & 7) * 8;    // read-side XOR mask (elems)

  const int t0 = j * 256;
  const int qb = t0 + w * 32;              // this wave's first Q row
  const int nblk = (t0 + 256) >> 6;        // KV blocks to process

  bf16x8 aq[2][2];
#pragma unroll
  for (int m = 0; m < 2; ++m)
#pragma unroll
    for (int sl = 0; sl < 2; ++sl)
      aq[m][sl] = ld_frag(qp + (size_t)(qb + m * 16 + lc) * HD_ + sl * 32 + lk * 8);

  f32x4 o[2][4] = {};
  float mr[2][4], lr[2][4];
#pragma unroll
  for (int m = 0; m < 2; ++m)
#pragma unroll
    for (int r = 0; r < 4; ++r) { mr[m][r] = -1e30f; lr[m][r] = 0.f; }

  // prologue: stage KV block 0 into buf 0
  gload_lds16(kp + (size_t)(8 * w + srow) * HD_ + sco, &kl[0][w * 512]);
  gload_lds16(vp + (size_t)(8 * w + srow) * T_ + sco, &vl[0][w * 512]);
  __syncthreads();

  int buf = 0;
  for (int kb = 0; kb < nblk; ++kb) {
    const int kv0 = kb * 64;
    if (kb + 1 < nblk) {  // stage next block into other buffer
      const int kvn = kv0 + 64;
      gload_lds16(kp + (size_t)(kvn + 8 * w + srow) * HD_ + sco, &kl[buf ^ 1][w * 512]);
      gload_lds16(vp + (size_t)(8 * w + srow) * T_ + kvn + sco, &vl[buf ^ 1][w * 512]);
    }
    if (kv0 < qb + 32) {  // wave-uniform causal skip
      // K frags from LDS (swizzled read)
      bf16x8 kf[4][2];
#pragma unroll
      for (int n = 0; n < 4; ++n)
#pragma unroll
        for (int sl = 0; sl < 2; ++sl)
          kf[n][sl] = ld_frag(&kl[buf][(n * 16 + lc) * 64 + ((sl * 32 + lk * 8) ^ rdm)]);
      // S = Q K^T : 32 q-rows x 64 kv
      f32x4 s[2][4] = {};
      __builtin_amdgcn_s_setprio(1);
#pragma unroll
      for (int m = 0; m < 2; ++m)
#pragma unroll
        for (int n = 0; n < 4; ++n) {
          s[m][n] = __builtin_amdgcn_mfma_f32_16x16x32_bf16(aq[m][0], kf[n][0], s[m][n], 0, 0, 0);
          s[m][n] = __builtin_amdgcn_mfma_f32_16x16x32_bf16(aq[m][1], kf[n][1], s[m][n], 0, 0, 0);
        }
      __builtin_amdgcn_s_setprio(0);
      // V frags (issue early; consumed by PV)
      bf16x8 vf[4][2];
#pragma unroll
      for (int n = 0; n < 4; ++n)
#pragma unroll
        for (int ks = 0; ks < 2; ++ks)
          vf[n][ks] = ld_frag(&vl[buf][(n * 16 + lc) * 64 + ((ks * 32 + lk * 8) ^ rdm)]);
      // causal mask
      if (kv0 + 63 > qb) {
#pragma unroll
        for (int m = 0; m < 2; ++m)
#pragma unroll
          for (int n = 0; n < 4; ++n) {
            const int kv = kv0 + n * 16 + lc;
#pragma unroll
            for (int r = 0; r < 4; ++r)
              if (kv > qb + m * 16 + lk * 4 + r) s[m][n][r] = -1e30f;
          }
      }
      // online softmax (exp2 domain) with deferred rescale (T13)
      float pm[2][4];
      int need = 0;
#pragma unroll
      for (int m = 0; m < 2; ++m)
#pragma unroll
        for (int r = 0; r < 4; ++r) {
          float v = fmaxf(fmaxf(s[m][0][r], s[m][1][r]), fmaxf(s[m][2][r], s[m][3][r]));
          v = rmax16(v);
          pm[m][r] = v;
          need |= (v - mr[m][r] > 8.f) ? 1 : 0;
        }
      if (__any(need)) {
        float al[2][4];
#pragma unroll
        for (int m = 0; m < 2; ++m)
#pragma unroll
          for (int r = 0; r < 4; ++r) {
            const float mn = fmaxf(mr[m][r], pm[m][r]);
            al[m][r] = exp2f(mr[m][r] - mn);
            mr[m][r] = mn;
            lr[m][r] *= al[m][r];
          }
#pragma unroll
        for (int m = 0; m < 2; ++m)
#pragma unroll
          for (int n = 0; n < 4; ++n)
#pragma unroll
            for (int r = 0; r < 4; ++r)
              o[m][n][r] *= al[m][r];
      }
      float rs[2][4] = {};
#pragma unroll
      for (int m = 0; m < 2; ++m)
#pragma unroll
        for (int n = 0; n < 4; ++n)
#pragma unroll
          for (int r = 0; r < 4; ++r) {
            const float p = exp2f(s[m][n][r] - mr[m][r]);
            s[m][n][r] = p;
            rs[m][r] += p;
          }
#pragma unroll
      for (int m = 0; m < 2; ++m)
#pragma unroll
        for (int r = 0; r < 4; ++r)
          lr[m][r] += rsum16(rs[m][r]);
      // P (C-layout) -> LDS -> A-layout frags (per-wave region, no barrier)
#pragma unroll
      for (int m = 0; m < 2; ++m)
#pragma unroll
        for (int n = 0; n < 4; ++n)
#pragma unroll
          for (int r = 0; r < 4; ++r)
            pt[w][m * 16 + lk * 4 + r][n * 16 + lc] = tobf(s[m][n][r]);
      bf16x8 pa[2][2];
#pragma unroll
      for (int m = 0; m < 2; ++m)
#pragma unroll
        for (int ks = 0; ks < 2; ++ks)
          pa[m][ks] = ld_frag(&ptw[(m * 16 + lc) * 72 + ks * 32 + lk * 8]);
      // O += P V
      __builtin_amdgcn_s_setprio(1);
#pragma unroll
      for (int m = 0; m < 2; ++m)
#pragma unroll
        for (int n = 0; n < 4; ++n) {
          o[m][n] = __builtin_amdgcn_mfma_f32_16x16x32_bf16(pa[m][0], vf[n][0], o[m][n], 0, 0, 0);
          o[m][n] = __builtin_amdgcn_mfma_f32_16x16x32_bf16(pa[m][1], vf[n][1], o[m][n], 0, 0, 0);
        }
      __builtin_amdgcn_s_setprio(0);
    }
    __syncthreads();
    buf ^= 1;
  }

  float invl[2][4];
#pragma unroll
  for (int m = 0; m < 2; ++m)
#pragma unroll
    for (int r = 0; r < 4; ++r) invl[m][r] = 1.f / lr[m][r];
#pragma unroll
  for (int m = 0; m < 2; ++m)
#pragma unroll
    for (int n = 0; n < 4; ++n)
#pragma unroll
      for (int r = 0; r < 4; ++r) {
        const int t = qb + m * 16 + lk * 4 + r;
        yb[(size_t)t * E_ + n * 16 + lc] = tobf(o[m][n][r] * invl[m][r]);
      }
}

// ---------------- launch ----------------

extern "C" void kernel_launch(void* const* d_in, const int* in_sizes, int n_in,
                              void* d_out, int out_size, void* d_ws, size_t ws_size,
                              hipStream_t stream) {
  const float* x  = (const float*)d_in[0];
  const float* Wa = (const float*)d_in[1];
  const float* ba = (const float*)d_in[2];
  const float* Wp = (const float*)d_in[3];
  const float* bp = (const float*)d_in[4];
  float* out = (float*)d_out;

  u16* ws   = (u16*)d_ws;
  u16* xb   = ws;                                  // 8M  (x bf16; later y bf16)
  u16* waT  = xb  + (size_t)8 * 1024 * 1024;       // 3M  (W_attn^T bf16)
  u16* wpT  = waT + (size_t)3 * 1024 * 1024;       // 1M  (W_proj^T bf16)
  u16* qws  = wpT + (size_t)1024 * 1024;           // 8M  q [B,H,T,HD]
  u16* kws  = qws + (size_t)8 * 1024 * 1024;       // 8M  k [B,H,T,HD]
  u16* vtws = kws + (size_t)8 * 1024 * 1024;       // 8M  v^T [B,H,HD,T]
  u16* yws  = xb;                                  // alias

  cvt_bf16_kernel<<<dim3(8192), dim3(256), 0, stream>>>(x, xb, 8 * 1024 * 1024);
  transpose_cvt_kernel<<<dim3(96, 32), dim3(32, 8), 0, stream>>>(Wa, waT, 1024, 3072);
  transpose_cvt_kernel<<<dim3(32, 32), dim3(32, 8), 0, stream>>>(Wp, wpT, 1024, 1024);

  gemm_kernel<0><<<dim3(64, 24), dim3(256), 0, stream>>>(xb, waT, ba, qws, kws, vtws, nullptr);
  attn_kernel<<<dim3(512), dim3(512), 0, stream>>>(qws, kws, vtws, yws);
  gemm_kernel<1><<<dim3(64, 8), dim3(256), 0, stream>>>(yws, wpT, bp, nullptr, nullptr, nullptr, out);
}

// Round 8
// 199.966 us; speedup vs baseline: 1.9229x; 1.1330x over previous
//
#include <hip/hip_runtime.h>
#include <hip/hip_bf16.h>
#include <stdint.h>

// Fused causal self-attention block: qkv GEMM -> flash attention -> proj GEMM.
// B=4 T=2048 E=1024 H=16 HD=64. All matmuls bf16 MFMA, fp32 accumulate.
// Attention: 32x32 swapped-QK (mfma(K,Q)) with fully in-register softmax.

#define B_  4
#define T_  2048
#define E_  1024
#define H_  16
#define HD_ 64

typedef unsigned short u16;
typedef __bf16 bf16x8 __attribute__((ext_vector_type(8)));
typedef float f32x4 __attribute__((ext_vector_type(4)));
typedef float f32x16 __attribute__((ext_vector_type(16)));

struct alignas(8) us4 { u16 x, y, z, w; };

// native bf16 convert (compiler emits v_cvt_pk_bf16_f32; RNE)
__device__ __forceinline__ u16 tobf(float f) {
  union { __bf16 h; u16 u; } c;
  c.h = (__bf16)f;
  return c.u;
}

__device__ __forceinline__ void gload_lds16(const void* g, void* l) {
  auto gp = reinterpret_cast<const __attribute__((address_space(1))) uint32_t*>(
      reinterpret_cast<uintptr_t>(g));
  auto lp = reinterpret_cast<__attribute__((address_space(3))) uint32_t*>(
      reinterpret_cast<uintptr_t>(l));
  __builtin_amdgcn_global_load_lds(gp, lp, 16, 0, 0);
}

__device__ __forceinline__ bf16x8 ld_frag(const u16* p) {
  return *reinterpret_cast<const bf16x8*>(p);
}

// ---------------- conversion kernels ----------------

__global__ void cvt_bf16_kernel(const float* __restrict__ in, u16* __restrict__ out, int n) {
  int i = (blockIdx.x * blockDim.x + threadIdx.x) * 4;
  if (i >= n) return;
  float4 v = *reinterpret_cast<const float4*>(in + i);
  us4 o = { tobf(v.x), tobf(v.y), tobf(v.z), tobf(v.w) };
  *reinterpret_cast<us4*>(out + i) = o;
}

// in: [K][N] f32 row-major -> out: [N][K] bf16 (B^T layout for GEMM)
__global__ void transpose_cvt_kernel(const float* __restrict__ in, u16* __restrict__ out,
                                     int K, int N) {
  __shared__ u16 tile[32][33];
  int n0 = blockIdx.x * 32, k0 = blockIdx.y * 32;
  int tx = threadIdx.x, ty = threadIdx.y;  // (32,8)
#pragma unroll
  for (int i = 0; i < 32; i += 8)
    tile[ty + i][tx] = tobf(in[(size_t)(k0 + ty + i) * N + n0 + tx]);
  __syncthreads();
#pragma unroll
  for (int i = 0; i < 32; i += 8)
    out[(size_t)(n0 + ty + i) * K + k0 + tx] = tile[tx][ty + i];
}

// ---------------- GEMM (m97-style 128x128 tile, BK=32) ----------------

template <int MODE>
__launch_bounds__(256)
__global__ void gemm_kernel(const u16* __restrict__ A, const u16* __restrict__ Bt,
                            const float* __restrict__ bias,
                            u16* __restrict__ qws, u16* __restrict__ kws,
                            u16* __restrict__ vtws, float* __restrict__ out) {
  constexpr int K = 1024, BK = 32;
  __shared__ u16 As[128 * BK];
  __shared__ u16 Bs[128 * BK];
  const int tid = threadIdx.x;
  const int wid = tid >> 6, lane = tid & 63;
  const int wm = wid >> 1, wn = wid & 1;
  const int row0 = blockIdx.x * 128, col0 = blockIdx.y * 128;

  f32x4 acc[4][4] = {};

  const int sr = lane >> 2;
  const int sc = (lane & 3) * 8;
  const int lrow = lane & 15;
  const int lkb = (lane >> 4) * 8;

  for (int k0 = 0; k0 < K; k0 += BK) {
#pragma unroll
    for (int c = 0; c < 2; ++c) {
      int chunk = wid * 2 + c;
      int r = chunk * 16 + sr;
      gload_lds16(A + (size_t)(row0 + r) * K + k0 + sc, &As[chunk * 512]);
      gload_lds16(Bt + (size_t)(col0 + r) * K + k0 + sc, &Bs[chunk * 512]);
    }
    __syncthreads();
    bf16x8 af[4], bf[4];
#pragma unroll
    for (int i = 0; i < 4; ++i) {
      af[i] = ld_frag(&As[(wm * 64 + i * 16 + lrow) * BK + lkb]);
      bf[i] = ld_frag(&Bs[(wn * 64 + i * 16 + lrow) * BK + lkb]);
    }
#pragma unroll
    for (int i = 0; i < 4; ++i)
#pragma unroll
      for (int j = 0; j < 4; ++j)
        acc[i][j] = __builtin_amdgcn_mfma_f32_16x16x32_bf16(af[i], bf[j], acc[i][j], 0, 0, 0);
    __syncthreads();
  }

#pragma unroll
  for (int mi = 0; mi < 4; ++mi) {
#pragma unroll
    for (int ni = 0; ni < 4; ++ni) {
      const int gr0 = row0 + wm * 64 + mi * 16 + (lane >> 4) * 4;
      const int gc = col0 + wn * 64 + ni * 16 + (lane & 15);
      const float bv = bias[gc];
      f32x4 v = acc[mi][ni];
      if constexpr (MODE == 0) {
        const int part = gc >> 10;          // 0=q 1=k 2=v
        const int e = gc & 1023;
        const int h = e >> 6, d = e & 63;
#pragma unroll
        for (int r = 0; r < 4; ++r) {
          const int m = gr0 + r;
          const int b = m >> 11, t = m & 2047;
          const float val = v[r] + bv;
          const size_t bh = (size_t)(b * H_ + h);
          if (part == 0)
            // fold 1/sqrt(64) * log2(e): softmax done in exp2 domain
            qws[(bh * T_ + t) * HD_ + d] = tobf(val * 0.1803368801f);
          else if (part == 1)
            kws[(bh * T_ + t) * HD_ + d] = tobf(val);
          else
            vtws[(bh * HD_ + d) * T_ + t] = tobf(val);          // V transposed
        }
      } else {
#pragma unroll
        for (int r = 0; r < 4; ++r) {
          const int m = gr0 + r;
          out[(size_t)m * E_ + gc] = v[r] + bv;
        }
      }
    }
  }
}

// ---------------- flash attention (32x32 swapped-QK, in-register softmax) ---
// grid = 1024 blocks x 256 threads (4 waves). Block: head bh = c>>2, Q-tile of
// 128 rows, tile j chosen so each dispatch slot's 4 tiles sum to constant work.
// Wave owns 32 q rows. QK^T computed swapped (A=K, B=Q, 32x32x16) so each lane
// holds a full q-row (q = lane&31) -> softmax is in-lane + one shfl_xor(32);
// stats are 2 scalars/lane. P redistributed to PV A-frags in-register via
// bf16 pack + 4 shfl_xor + selects (no LDS roundtrip). K/V tiles (32 kv)
// reg-staged into LDS with odd-dword-stride padded rows (conflict-free b64
// reads), double-buffered, 1 barrier/tile. Defer-max (T13); setprio (T5).

__launch_bounds__(256, 4)
__global__ void attn_kernel(const u16* __restrict__ q, const u16* __restrict__ k,
                            const u16* __restrict__ vt, u16* __restrict__ y) {
  __shared__ u16 kl[2][32 * 68];   // K tile: 32 kv rows x 64 hd, rows padded to 136B
  __shared__ u16 vl[2][64 * 36];   // V^T tile: 64 d rows x 32 kv, rows padded to 72B
  const int tid = threadIdx.x, w = tid >> 6, lane = tid & 63;
  const int l31 = lane & 31, hi = lane >> 5;
  const bool H = hi != 0;
  const int bid = blockIdx.x;
  const int c = bid & 255, q4 = bid >> 8;
  const int bh = c >> 2, a = c & 3;
  const int j = (q4 < 2) ? (a + 4 * q4) : (15 - a - 4 * (q4 - 2));  // balanced
  const u16* qp = q + (size_t)bh * T_ * HD_;
  const u16* kp = k + (size_t)bh * T_ * HD_;
  const u16* vp = vt + (size_t)bh * HD_ * T_;
  const int b = bh >> 4, h = bh & 15;
  u16* yb = y + (size_t)b * T_ * E_ + h * HD_;

  const int t0 = j * 128;
  const int qbw = t0 + w * 32;          // wave's first q row
  const int nblk = (t0 + 128) >> 5;     // 32-kv tiles

  // Q fragments (B-operand): lane holds Q[qbw + l31][slot*16 + hi*8 + e]
  bf16x8 aq[4];
#pragma unroll
  for (int slot = 0; slot < 4; ++slot)
    aq[slot] = ld_frag(qp + (size_t)(qbw + l31) * HD_ + slot * 16 + hi * 8);

  f32x16 o0 = {}, o1 = {};              // O[q=crow(r,hi)][d = dt*32 + l31]
  float mr = -1e30f, lr = 0.f;          // stats for row q = l31 (lane-local)

  // staging assignments
  const int skv = w * 8 + (lane >> 3);  // K: 8 rows/wave, 8 lanes x 16B per row
  const int skc = (lane & 7) * 8;
  const int svd = w * 16 + (lane >> 2); // V: 16 rows/wave, 4 lanes x 16B per row
  const int svc = (lane & 3) * 8;

  uint4 kreg = *(const uint4*)(kp + (size_t)skv * HD_ + skc);
  uint4 vreg = *(const uint4*)(vp + (size_t)svd * T_ + svc);

  int buf = 0;
  for (int kb = 0; kb < nblk; ++kb) {
    const int kv0 = kb * 32;
    // write staged tile to LDS (2x b64 each; padded rows)
    {
      u16* kd = &kl[buf][skv * 68 + skc];
      uint2 ka = {kreg.x, kreg.y}, kb2 = {kreg.z, kreg.w};
      *(uint2*)kd = ka;
      *(uint2*)(kd + 4) = kb2;
      u16* vd = &vl[buf][svd * 36 + svc];
      uint2 va = {vreg.x, vreg.y}, vb2 = {vreg.z, vreg.w};
      *(uint2*)vd = va;
      *(uint2*)(vd + 4) = vb2;
    }
    // issue next tile's global loads (latency hides under compute — T14)
    if (kb + 1 < nblk) {
      const int kvn = kv0 + 32;
      kreg = *(const uint4*)(kp + (size_t)(kvn + skv) * HD_ + skc);
      vreg = *(const uint4*)(vp + (size_t)svd * T_ + kvn + svc);
    }
    __syncthreads();

    if (kv0 <= qbw + 31) {              // wave-uniform causal skip
      // S = K·Q^T (swapped): lane holds S[kv=crow(r,hi)][q=l31]... i.e. per
      // lane: 16 kv values of q-row l31.
      f32x16 s = {};
      __builtin_amdgcn_s_setprio(1);
#pragma unroll
      for (int slot = 0; slot < 4; ++slot) {
        union { uint2 d[2]; bf16x8 v; } kf;
        const u16* kr = &kl[buf][l31 * 68 + slot * 16 + hi * 8];
        kf.d[0] = *(const uint2*)kr;
        kf.d[1] = *(const uint2*)(kr + 4);
        s = __builtin_amdgcn_mfma_f32_32x32x16_bf16(kf.v, aq[slot], s, 0, 0, 0);
      }
      __builtin_amdgcn_s_setprio(0);

      // causal mask: kv = kv0 + crow(r,hi), q = qbw + l31
      if (kv0 + 31 > qbw) {
        const int qq = qbw + l31;
#pragma unroll
        for (int r = 0; r < 16; ++r) {
          const int kv = kv0 + (r & 3) + 8 * (r >> 2) + 4 * hi;
          if (kv > qq) s[r] = -1e30f;
        }
      }

      // row max: in-lane tree + partner half
      float t[8];
#pragma unroll
      for (int r = 0; r < 8; ++r) t[r] = fmaxf(s[r], s[r + 8]);
#pragma unroll
      for (int r = 0; r < 4; ++r) t[r] = fmaxf(t[r], t[r + 4]);
      float pm = fmaxf(fmaxf(t[0], t[1]), fmaxf(t[2], t[3]));
      pm = fmaxf(pm, __shfl_xor(pm, 32));

      // deferred rescale (T13)
      if (__any(pm > mr + 8.f)) {
        const float mn = fmaxf(mr, pm);
        const float al = exp2f(mr - mn);
        mr = mn;
        lr *= al;
#pragma unroll
        for (int r = 0; r < 16; ++r) {
          const float ab = __shfl(al, ((r & 3) + 8 * (r >> 2) + 4 * hi) + (lane & 32));
          o0[r] *= ab;
          o1[r] *= ab;
        }
      }

      // P = exp2(S - mr), row sum
      float p[16];
      float rs = 0.f;
#pragma unroll
      for (int r = 0; r < 16; ++r) {
        p[r] = exp2f(s[r] - mr);
        rs += p[r];
      }
      rs += __shfl_xor(rs, 32);
      lr += rs;

      // pack P to bf16 pairs; redistribute to PV A-fragments in-register.
      // c-words: cw[i] = (p[2i], p[2i+1]); kv coverage per hi per derivation.
      unsigned cw[8];
#pragma unroll
      for (int i = 0; i < 8; ++i) {
        union { __bf16 hh[2]; unsigned u; } pk;
        pk.hh[0] = (__bf16)p[2 * i];
        pk.hh[1] = (__bf16)p[2 * i + 1];
        cw[i] = pk.u;
      }
      const unsigned r0 = __shfl_xor(H ? cw[0] : cw[2], 32);
      const unsigned r1 = __shfl_xor(H ? cw[1] : cw[3], 32);
      const unsigned r2 = __shfl_xor(H ? cw[4] : cw[6], 32);
      const unsigned r3 = __shfl_xor(H ? cw[5] : cw[7], 32);
      union PU { unsigned u[4]; bf16x8 v; } pa0, pa1;
      pa0.u[0] = H ? r0 : cw[0];
      pa0.u[1] = H ? r1 : cw[1];
      pa0.u[2] = H ? cw[2] : r0;
      pa0.u[3] = H ? cw[3] : r1;
      pa1.u[0] = H ? r2 : cw[4];
      pa1.u[1] = H ? r3 : cw[5];
      pa1.u[2] = H ? cw[6] : r2;
      pa1.u[3] = H ? cw[7] : r3;

      // O += P·V : B-frags from vl rows d = dt*32 + l31, k = ks*16 + hi*8 + e
      __builtin_amdgcn_s_setprio(1);
      {
        union { uint2 d[2]; bf16x8 v; } vf;
        const u16* vr0 = &vl[buf][l31 * 36 + hi * 8];
        vf.d[0] = *(const uint2*)vr0;
        vf.d[1] = *(const uint2*)(vr0 + 4);
        o0 = __builtin_amdgcn_mfma_f32_32x32x16_bf16(pa0.v, vf.v, o0, 0, 0, 0);
        vf.d[0] = *(const uint2*)(vr0 + 16);
        vf.d[1] = *(const uint2*)(vr0 + 20);
        o0 = __builtin_amdgcn_mfma_f32_32x32x16_bf16(pa1.v, vf.v, o0, 0, 0, 0);
        const u16* vr1 = &vl[buf][(32 + l31) * 36 + hi * 8];
        vf.d[0] = *(const uint2*)vr1;
        vf.d[1] = *(const uint2*)(vr1 + 4);
        o1 = __builtin_amdgcn_mfma_f32_32x32x16_bf16(pa0.v, vf.v, o1, 0, 0, 0);
        vf.d[0] = *(const uint2*)(vr1 + 16);
        vf.d[1] = *(const uint2*)(vr1 + 20);
        o1 = __builtin_amdgcn_mfma_f32_32x32x16_bf16(pa1.v, vf.v, o1, 0, 0, 0);
      }
      __builtin_amdgcn_s_setprio(0);
    }
    buf ^= 1;
  }

  // normalize + write: O row q=crow(r,hi) needs 1/lr from lane q (|32 half)
  const float il = 1.f / lr;
#pragma unroll
  for (int r = 0; r < 16; ++r) {
    const int cr = (r & 3) + 8 * (r >> 2) + 4 * hi;
    const float li = __shfl(il, cr + (lane & 32));
    const size_t row = (size_t)(qbw + cr) * E_;
    yb[row + l31] = tobf(o0[r] * li);
    yb[row + 32 + l31] = tobf(o1[r] * li);
  }
}

// ---------------- launch ----------------

extern "C" void kernel_launch(void* const* d_in, const int* in_sizes, int n_in,
                              void* d_out, int out_size, void* d_ws, size_t ws_size,
                              hipStream_t stream) {
  const float* x  = (const float*)d_in[0];
  const float* Wa = (const float*)d_in[1];
  const float* ba = (const float*)d_in[2];
  const float* Wp = (const float*)d_in[3];
  const float* bp = (const float*)d_in[4];
  float* out = (float*)d_out;

  u16* ws   = (u16*)d_ws;
  u16* xb   = ws;                                  // 8M  (x bf16; later y bf16)
  u16* waT  = xb  + (size_t)8 * 1024 * 1024;       // 3M  (W_attn^T bf16)
  u16* wpT  = waT + (size_t)3 * 1024 * 1024;       // 1M  (W_proj^T bf16)
  u16* qws  = wpT + (size_t)1024 * 1024;           // 8M  q [B,H,T,HD]
  u16* kws  = qws + (size_t)8 * 1024 * 1024;       // 8M  k [B,H,T,HD]
  u16* vtws = kws + (size_t)8 * 1024 * 1024;       // 8M  v^T [B,H,HD,T]
  u16* yws  = xb;                                  // alias

  cvt_bf16_kernel<<<dim3(8192), dim3(256), 0, stream>>>(x, xb, 8 * 1024 * 1024);
  transpose_cvt_kernel<<<dim3(96, 32), dim3(32, 8), 0, stream>>>(Wa, waT, 1024, 3072);
  transpose_cvt_kernel<<<dim3(32, 32), dim3(32, 8), 0, stream>>>(Wp, wpT, 1024, 1024);

  gemm_kernel<0><<<dim3(64, 24), dim3(256), 0, stream>>>(xb, waT, ba, qws, kws, vtws, nullptr);
  attn_kernel<<<dim3(1024), dim3(256), 0, stream>>>(qws, kws, vtws, yws);
  gemm_kernel<1><<<dim3(64, 8), dim3(256), 0, stream>>>(yws, wpT, bp, nullptr, nullptr, nullptr, out);
}

// Round 9
// 195.625 us; speedup vs baseline: 1.9655x; 1.0222x over previous
//
#include <hip/hip_runtime.h>
#include <hip/hip_bf16.h>
#include <stdint.h>

// Fused causal self-attention block: qkv GEMM -> flash attention -> proj GEMM.
// B=4 T=2048 E=1024 H=16 HD=64. All matmuls bf16 MFMA, fp32 accumulate.
// GEMMs: 128x256 tile, BK=64, 8 waves, 3-deep K-pipeline with counted vmcnt
// (T3+T4), LDS slot-XOR swizzle both-sides (T2/T21), setprio (T5).
// Attention: 32x32 swapped-QK (mfma(K,Q)) with fully in-register softmax.

#define B_  4
#define T_  2048
#define E_  1024
#define H_  16
#define HD_ 64

typedef unsigned short u16;
typedef __bf16 bf16x8 __attribute__((ext_vector_type(8)));
typedef float f32x4 __attribute__((ext_vector_type(4)));
typedef float f32x16 __attribute__((ext_vector_type(16)));

struct alignas(8) us4 { u16 x, y, z, w; };

// native bf16 convert (compiler emits v_cvt_pk_bf16_f32; RNE)
__device__ __forceinline__ u16 tobf(float f) {
  union { __bf16 h; u16 u; } c;
  c.h = (__bf16)f;
  return c.u;
}

__device__ __forceinline__ void gload_lds16(const void* g, void* l) {
  // global -> LDS direct, 16B/lane (wave-uniform LDS base + lane*16).
  auto gp = reinterpret_cast<const __attribute__((address_space(1))) uint32_t*>(
      reinterpret_cast<uintptr_t>(g));
  auto lp = reinterpret_cast<__attribute__((address_space(3))) uint32_t*>(
      reinterpret_cast<uintptr_t>(l));
  __builtin_amdgcn_global_load_lds(gp, lp, 16, 0, 0);
}

__device__ __forceinline__ bf16x8 ld_frag(const u16* p) {
  return *reinterpret_cast<const bf16x8*>(p);
}

// raw barrier + compiler memory fence (NOT __syncthreads: that drains vmcnt(0)
// and kills the counted-vmcnt pipeline)
#define BARRIER() do { __builtin_amdgcn_s_barrier(); asm volatile("" ::: "memory"); } while (0)

// ---------------- conversion kernels ----------------

__global__ void cvt_bf16_kernel(const float* __restrict__ in, u16* __restrict__ out, int n) {
  int i = (blockIdx.x * blockDim.x + threadIdx.x) * 4;
  if (i >= n) return;
  float4 v = *reinterpret_cast<const float4*>(in + i);
  us4 o = { tobf(v.x), tobf(v.y), tobf(v.z), tobf(v.w) };
  *reinterpret_cast<us4*>(out + i) = o;
}

// in: [K][N] f32 row-major -> out: [N][K] bf16 (B^T layout for GEMM)
__global__ void transpose_cvt_kernel(const float* __restrict__ in, u16* __restrict__ out,
                                     int K, int N) {
  __shared__ u16 tile[32][33];
  int n0 = blockIdx.x * 32, k0 = blockIdx.y * 32;
  int tx = threadIdx.x, ty = threadIdx.y;  // (32,8)
#pragma unroll
  for (int i = 0; i < 32; i += 8)
    tile[ty + i][tx] = tobf(in[(size_t)(k0 + ty + i) * N + n0 + tx]);
  __syncthreads();
#pragma unroll
  for (int i = 0; i < 32; i += 8)
    out[(size_t)(n0 + ty + i) * K + k0 + tx] = tile[tx][ty + i];
}

// ---------------- GEMM: 128x256 tile, BK=64, 8 waves, 3-buf pipeline -------
// Per K-tile: 4 phases of {stage-issue || ds_read frags || barrier ||
// setprio(1) 8xMFMA setprio(0) || barrier}; vmcnt(6) once per K-tile (tile
// t+1's 6 loads drained, tile t+2's 6 stay in flight across the barrier).
// LDS tiles slot-XOR swizzled: slot' = slot ^ (row&7); written via linear
// global_load_lds dest + inverse-permuted GLOBAL source; read with same XOR.

template <int MODE>
__launch_bounds__(512, 2)
__global__ void gemm_kernel(const u16* __restrict__ A, const u16* __restrict__ Bt,
                            const float* __restrict__ bias,
                            u16* __restrict__ qws, u16* __restrict__ kws,
                            u16* __restrict__ vtws, float* __restrict__ out) {
  constexpr int K = 1024, NT = 16;   // 16 K-tiles of 64
  __shared__ u16 As[3][128 * 64];    // 48KB
  __shared__ u16 Bs[3][256 * 64];    // 96KB
  const int tid = threadIdx.x;
  const int wid = tid >> 6, lane = tid & 63;
  const int wm = wid >> 2, wn = wid & 3;     // 2M x 4N waves; 64x64 out/wave
  const int row0 = blockIdx.x * 128, col0 = blockIdx.y * 256;

  // staging constants: chunk = 8 rows x 64 elems (1KB), 1 gload inst/wave
  const int srow = lane >> 3;                 // row within chunk
  const int sgslot = (lane & 7) ^ srow;       // inverse-swizzled source slot
  const int arow = wid * 16 + srow;           // A chunk c: rows wid*16 + c*8
  const int brow = wid * 32 + srow;           // B chunk c: rows wid*32 + c*8
  // read constants
  const int lrow = lane & 15;
  const int lks = lane >> 4;                  // 0..3 (16B slot within K-half)
  const int r7 = lrow & 7;

#define STAGE_A(bufi, kt, c)                                                    \
  gload_lds16(A + (size_t)(row0 + arow + (c) * 8) * K + (kt) * 64 + sgslot * 8, \
              &As[bufi][(wid * 2 + (c)) * 512])
#define STAGE_B(bufi, kt, c)                                                    \
  gload_lds16(Bt + (size_t)(col0 + brow + (c) * 8) * K + (kt) * 64 + sgslot * 8,\
              &Bs[bufi][(wid * 4 + (c)) * 512])
#define RDA(i, kk) ld_frag(&Ab[(wm * 64 + (i) * 16 + lrow) * 64 + ((((kk) * 4 + lks) ^ r7) * 8)])
#define RDB(j, kk) ld_frag(&Bb[(wn * 64 + (j) * 16 + lrow) * 64 + ((((kk) * 4 + lks) ^ r7) * 8)])

  f32x4 acc[4][4] = {};

  // prologue: stage tiles 0 and 1 (6 loads each)
  STAGE_A(0, 0, 0); STAGE_A(0, 0, 1);
  STAGE_B(0, 0, 0); STAGE_B(0, 0, 1); STAGE_B(0, 0, 2); STAGE_B(0, 0, 3);
  STAGE_A(1, 1, 0); STAGE_A(1, 1, 1);
  STAGE_B(1, 1, 0); STAGE_B(1, 1, 1); STAGE_B(1, 1, 2); STAGE_B(1, 1, 3);
  asm volatile("s_waitcnt vmcnt(6)" ::: "memory");  // tile 0 landed
  BARRIER();

  int rb = 0, sb = 2;
  for (int t = 0; t < NT; ++t) {
    const bool hn = (t + 2) < NT;
    const int kt2 = t + 2;
    const u16* Ab = &As[rb][0];
    const u16* Bb = &Bs[rb][0];
    bf16x8 af[4], bf[4];

    // ---- phase 0: stage A(t+2); read af0-1,bf0-3 (kk=0); MFMA rows 0-1 ----
    if (hn) { STAGE_A(sb, kt2, 0); STAGE_A(sb, kt2, 1); }
    af[0] = RDA(0, 0); af[1] = RDA(1, 0);
    bf[0] = RDB(0, 0); bf[1] = RDB(1, 0); bf[2] = RDB(2, 0); bf[3] = RDB(3, 0);
    BARRIER();
    __builtin_amdgcn_s_setprio(1);
#pragma unroll
    for (int i = 0; i < 2; ++i)
#pragma unroll
      for (int j = 0; j < 4; ++j)
        acc[i][j] = __builtin_amdgcn_mfma_f32_16x16x32_bf16(af[i], bf[j], acc[i][j], 0, 0, 0);
    __builtin_amdgcn_s_setprio(0);
    BARRIER();

    // ---- phase 1: stage B0(t+2); read af2-3 (kk=0); MFMA rows 2-3 ----
    if (hn) STAGE_B(sb, kt2, 0);
    af[2] = RDA(2, 0); af[3] = RDA(3, 0);
    BARRIER();
    __builtin_amdgcn_s_setprio(1);
#pragma unroll
    for (int i = 2; i < 4; ++i)
#pragma unroll
      for (int j = 0; j < 4; ++j)
        acc[i][j] = __builtin_amdgcn_mfma_f32_16x16x32_bf16(af[i], bf[j], acc[i][j], 0, 0, 0);
    __builtin_amdgcn_s_setprio(0);
    BARRIER();

    // ---- phase 2: stage B1-2(t+2); read af0-1,bf0-3 (kk=1); MFMA rows 0-1 --
    if (hn) { STAGE_B(sb, kt2, 1); STAGE_B(sb, kt2, 2); }
    af[0] = RDA(0, 1); af[1] = RDA(1, 1);
    bf[0] = RDB(0, 1); bf[1] = RDB(1, 1); bf[2] = RDB(2, 1); bf[3] = RDB(3, 1);
    BARRIER();
    __builtin_amdgcn_s_setprio(1);
#pragma unroll
    for (int i = 0; i < 2; ++i)
#pragma unroll
      for (int j = 0; j < 4; ++j)
        acc[i][j] = __builtin_amdgcn_mfma_f32_16x16x32_bf16(af[i], bf[j], acc[i][j], 0, 0, 0);
    __builtin_amdgcn_s_setprio(0);
    BARRIER();

    // ---- phase 3: stage B3(t+2); read af2-3 (kk=1); vmcnt; MFMA rows 2-3 --
    if (hn) STAGE_B(sb, kt2, 3);
    af[2] = RDA(2, 1); af[3] = RDA(3, 1);
    if (hn) asm volatile("s_waitcnt vmcnt(6)" ::: "memory");  // tile t+1 landed
    else    asm volatile("s_waitcnt vmcnt(0)" ::: "memory");  // tail drain
    BARRIER();
    __builtin_amdgcn_s_setprio(1);
#pragma unroll
    for (int i = 2; i < 4; ++i)
#pragma unroll
      for (int j = 0; j < 4; ++j)
        acc[i][j] = __builtin_amdgcn_mfma_f32_16x16x32_bf16(af[i], bf[j], acc[i][j], 0, 0, 0);
    __builtin_amdgcn_s_setprio(0);
    BARRIER();

    rb = (rb == 2) ? 0 : rb + 1;
    sb = (sb == 2) ? 0 : sb + 1;
  }
#undef STAGE_A
#undef STAGE_B
#undef RDA
#undef RDB

  // C/D layout: col = lane&15, row = (lane>>4)*4 + reg
#pragma unroll
  for (int mi = 0; mi < 4; ++mi) {
#pragma unroll
    for (int ni = 0; ni < 4; ++ni) {
      const int gr0 = row0 + wm * 64 + mi * 16 + (lane >> 4) * 4;
      const int gc = col0 + wn * 64 + ni * 16 + (lane & 15);
      const float bv = bias[gc];
      f32x4 v = acc[mi][ni];
      if constexpr (MODE == 0) {
        const int part = gc >> 10;          // 0=q 1=k 2=v
        const int e = gc & 1023;
        const int h = e >> 6, d = e & 63;
#pragma unroll
        for (int r = 0; r < 4; ++r) {
          const int m = gr0 + r;
          const int b = m >> 11, t = m & 2047;
          const float val = v[r] + bv;
          const size_t bh = (size_t)(b * H_ + h);
          if (part == 0)
            // fold 1/sqrt(64) * log2(e): softmax done in exp2 domain
            qws[(bh * T_ + t) * HD_ + d] = tobf(val * 0.1803368801f);
          else if (part == 1)
            kws[(bh * T_ + t) * HD_ + d] = tobf(val);
          else
            vtws[(bh * HD_ + d) * T_ + t] = tobf(val);          // V transposed
        }
      } else {
#pragma unroll
        for (int r = 0; r < 4; ++r) {
          const int m = gr0 + r;
          out[(size_t)m * E_ + gc] = v[r] + bv;
        }
      }
    }
  }
}

// ---------------- flash attention (32x32 swapped-QK, in-register softmax) ---
// grid = 1024 blocks x 256 threads (4 waves). Block: head bh = c>>2, Q-tile of
// 128 rows, tile j chosen so each dispatch slot's 4 tiles sum to constant work.
// Wave owns 32 q rows. QK^T computed swapped (A=K, B=Q, 32x32x16) so each lane
// holds a full q-row (q = lane&31) -> softmax is in-lane + one shfl_xor(32);
// stats are 2 scalars/lane. P redistributed to PV A-frags in-register via
// bf16 pack + 4 shfl_xor + selects (no LDS roundtrip). K/V tiles (32 kv)
// reg-staged into LDS with odd-dword-stride padded rows (conflict-free b64
// reads), double-buffered, 1 barrier/tile. Defer-max (T13); setprio (T5).

__launch_bounds__(256, 4)
__global__ void attn_kernel(const u16* __restrict__ q, const u16* __restrict__ k,
                            const u16* __restrict__ vt, u16* __restrict__ y) {
  __shared__ u16 kl[2][32 * 68];   // K tile: 32 kv rows x 64 hd, rows padded to 136B
  __shared__ u16 vl[2][64 * 36];   // V^T tile: 64 d rows x 32 kv, rows padded to 72B
  const int tid = threadIdx.x, w = tid >> 6, lane = tid & 63;
  const int l31 = lane & 31, hi = lane >> 5;
  const bool H = hi != 0;
  const int bid = blockIdx.x;
  const int c = bid & 255, q4 = bid >> 8;
  const int bh = c >> 2, a = c & 3;
  const int j = (q4 < 2) ? (a + 4 * q4) : (15 - a - 4 * (q4 - 2));  // balanced
  const u16* qp = q + (size_t)bh * T_ * HD_;
  const u16* kp = k + (size_t)bh * T_ * HD_;
  const u16* vp = vt + (size_t)bh * HD_ * T_;
  const int b = bh >> 4, h = bh & 15;
  u16* yb = y + (size_t)b * T_ * E_ + h * HD_;

  const int t0 = j * 128;
  const int qbw = t0 + w * 32;          // wave's first q row
  const int nblk = (t0 + 128) >> 5;     // 32-kv tiles

  // Q fragments (B-operand): lane holds Q[qbw + l31][slot*16 + hi*8 + e]
  bf16x8 aq[4];
#pragma unroll
  for (int slot = 0; slot < 4; ++slot)
    aq[slot] = ld_frag(qp + (size_t)(qbw + l31) * HD_ + slot * 16 + hi * 8);

  f32x16 o0 = {}, o1 = {};              // O[q=crow(r,hi)][d = dt*32 + l31]
  float mr = -1e30f, lr = 0.f;          // stats for row q = l31 (lane-local)

  // staging assignments
  const int skv = w * 8 + (lane >> 3);  // K: 8 rows/wave, 8 lanes x 16B per row
  const int skc = (lane & 7) * 8;
  const int svd = w * 16 + (lane >> 2); // V: 16 rows/wave, 4 lanes x 16B per row
  const int svc = (lane & 3) * 8;

  uint4 kreg = *(const uint4*)(kp + (size_t)skv * HD_ + skc);
  uint4 vreg = *(const uint4*)(vp + (size_t)svd * T_ + svc);

  int buf = 0;
  for (int kb = 0; kb < nblk; ++kb) {
    const int kv0 = kb * 32;
    // write staged tile to LDS (2x b64 each; padded rows)
    {
      u16* kd = &kl[buf][skv * 68 + skc];
      uint2 ka = {kreg.x, kreg.y}, kb2 = {kreg.z, kreg.w};
      *(uint2*)kd = ka;
      *(uint2*)(kd + 4) = kb2;
      u16* vd = &vl[buf][svd * 36 + svc];
      uint2 va = {vreg.x, vreg.y}, vb2 = {vreg.z, vreg.w};
      *(uint2*)vd = va;
      *(uint2*)(vd + 4) = vb2;
    }
    // issue next tile's global loads (latency hides under compute — T14)
    if (kb + 1 < nblk) {
      const int kvn = kv0 + 32;
      kreg = *(const uint4*)(kp + (size_t)(kvn + skv) * HD_ + skc);
      vreg = *(const uint4*)(vp + (size_t)svd * T_ + kvn + svc);
    }
    __syncthreads();

    if (kv0 <= qbw + 31) {              // wave-uniform causal skip
      // S = K·Q^T (swapped): lane holds 16 kv values of q-row l31.
      f32x16 s = {};
      __builtin_amdgcn_s_setprio(1);
#pragma unroll
      for (int slot = 0; slot < 4; ++slot) {
        union { uint2 d[2]; bf16x8 v; } kf;
        const u16* kr = &kl[buf][l31 * 68 + slot * 16 + hi * 8];
        kf.d[0] = *(const uint2*)kr;
        kf.d[1] = *(const uint2*)(kr + 4);
        s = __builtin_amdgcn_mfma_f32_32x32x16_bf16(kf.v, aq[slot], s, 0, 0, 0);
      }
      __builtin_amdgcn_s_setprio(0);

      // causal mask: kv = kv0 + crow(r,hi), q = qbw + l31
      if (kv0 + 31 > qbw) {
        const int qq = qbw + l31;
#pragma unroll
        for (int r = 0; r < 16; ++r) {
          const int kv = kv0 + (r & 3) + 8 * (r >> 2) + 4 * hi;
          if (kv > qq) s[r] = -1e30f;
        }
      }

      // row max: in-lane tree + partner half
      float t[8];
#pragma unroll
      for (int r = 0; r < 8; ++r) t[r] = fmaxf(s[r], s[r + 8]);
#pragma unroll
      for (int r = 0; r < 4; ++r) t[r] = fmaxf(t[r], t[r + 4]);
      float pm = fmaxf(fmaxf(t[0], t[1]), fmaxf(t[2], t[3]));
      pm = fmaxf(pm, __shfl_xor(pm, 32));

      // deferred rescale (T13)
      if (__any(pm > mr + 8.f)) {
        const float mn = fmaxf(mr, pm);
        const float al = exp2f(mr - mn);
        mr = mn;
        lr *= al;
#pragma unroll
        for (int r = 0; r < 16; ++r) {
          const float ab = __shfl(al, ((r & 3) + 8 * (r >> 2) + 4 * hi) + (lane & 32));
          o0[r] *= ab;
          o1[r] *= ab;
        }
      }

      // P = exp2(S - mr), row sum
      float p[16];
      float rs = 0.f;
#pragma unroll
      for (int r = 0; r < 16; ++r) {
        p[r] = exp2f(s[r] - mr);
        rs += p[r];
      }
      rs += __shfl_xor(rs, 32);
      lr += rs;

      // pack P to bf16 pairs; redistribute to PV A-fragments in-register.
      unsigned cw[8];
#pragma unroll
      for (int i = 0; i < 8; ++i) {
        union { __bf16 hh[2]; unsigned u; } pk;
        pk.hh[0] = (__bf16)p[2 * i];
        pk.hh[1] = (__bf16)p[2 * i + 1];
        cw[i] = pk.u;
      }
      const unsigned r0 = __shfl_xor(H ? cw[0] : cw[2], 32);
      const unsigned r1 = __shfl_xor(H ? cw[1] : cw[3], 32);
      const unsigned r2 = __shfl_xor(H ? cw[4] : cw[6], 32);
      const unsigned r3 = __shfl_xor(H ? cw[5] : cw[7], 32);
      union PU { unsigned u[4]; bf16x8 v; } pa0, pa1;
      pa0.u[0] = H ? r0 : cw[0];
      pa0.u[1] = H ? r1 : cw[1];
      pa0.u[2] = H ? cw[2] : r0;
      pa0.u[3] = H ? cw[3] : r1;
      pa1.u[0] = H ? r2 : cw[4];
      pa1.u[1] = H ? r3 : cw[5];
      pa1.u[2] = H ? cw[6] : r2;
      pa1.u[3] = H ? cw[7] : r3;

      // O += P·V : B-frags from vl rows d = dt*32 + l31, k = ks*16 + hi*8 + e
      __builtin_amdgcn_s_setprio(1);
      {
        union { uint2 d[2]; bf16x8 v; } vf;
        const u16* vr0 = &vl[buf][l31 * 36 + hi * 8];
        vf.d[0] = *(const uint2*)vr0;
        vf.d[1] = *(const uint2*)(vr0 + 4);
        o0 = __builtin_amdgcn_mfma_f32_32x32x16_bf16(pa0.v, vf.v, o0, 0, 0, 0);
        vf.d[0] = *(const uint2*)(vr0 + 16);
        vf.d[1] = *(const uint2*)(vr0 + 20);
        o0 = __builtin_amdgcn_mfma_f32_32x32x16_bf16(pa1.v, vf.v, o0, 0, 0, 0);
        const u16* vr1 = &vl[buf][(32 + l31) * 36 + hi * 8];
        vf.d[0] = *(const uint2*)vr1;
        vf.d[1] = *(const uint2*)(vr1 + 4);
        o1 = __builtin_amdgcn_mfma_f32_32x32x16_bf16(pa0.v, vf.v, o1, 0, 0, 0);
        vf.d[0] = *(const uint2*)(vr1 + 16);
        vf.d[1] = *(const uint2*)(vr1 + 20);
        o1 = __builtin_amdgcn_mfma_f32_32x32x16_bf16(pa1.v, vf.v, o1, 0, 0, 0);
      }
      __builtin_amdgcn_s_setprio(0);
    }
    buf ^= 1;
  }

  // normalize + write: O row q=crow(r,hi) needs 1/lr from lane q (|32 half)
  const float il = 1.f / lr;
#pragma unroll
  for (int r = 0; r < 16; ++r) {
    const int cr = (r & 3) + 8 * (r >> 2) + 4 * hi;
    const float li = __shfl(il, cr + (lane & 32));
    const size_t row = (size_t)(qbw + cr) * E_;
    yb[row + l31] = tobf(o0[r] * li);
    yb[row + 32 + l31] = tobf(o1[r] * li);
  }
}

// ---------------- launch ----------------

extern "C" void kernel_launch(void* const* d_in, const int* in_sizes, int n_in,
                              void* d_out, int out_size, void* d_ws, size_t ws_size,
                              hipStream_t stream) {
  const float* x  = (const float*)d_in[0];
  const float* Wa = (const float*)d_in[1];
  const float* ba = (const float*)d_in[2];
  const float* Wp = (const float*)d_in[3];
  const float* bp = (const float*)d_in[4];
  float* out = (float*)d_out;

  u16* ws   = (u16*)d_ws;
  u16* xb   = ws;                                  // 8M  (x bf16; later y bf16)
  u16* waT  = xb  + (size_t)8 * 1024 * 1024;       // 3M  (W_attn^T bf16)
  u16* wpT  = waT + (size_t)3 * 1024 * 1024;       // 1M  (W_proj^T bf16)
  u16* qws  = wpT + (size_t)1024 * 1024;           // 8M  q [B,H,T,HD]
  u16* kws  = qws + (size_t)8 * 1024 * 1024;       // 8M  k [B,H,T,HD]
  u16* vtws = kws + (size_t)8 * 1024 * 1024;       // 8M  v^T [B,H,HD,T]
  u16* yws  = xb;                                  // alias

  cvt_bf16_kernel<<<dim3(8192), dim3(256), 0, stream>>>(x, xb, 8 * 1024 * 1024);
  transpose_cvt_kernel<<<dim3(96, 32), dim3(32, 8), 0, stream>>>(Wa, waT, 1024, 3072);
  transpose_cvt_kernel<<<dim3(32, 32), dim3(32, 8), 0, stream>>>(Wp, wpT, 1024, 1024);

  gemm_kernel<0><<<dim3(64, 12), dim3(512), 0, stream>>>(xb, waT, ba, qws, kws, vtws, nullptr);
  attn_kernel<<<dim3(1024), dim3(256), 0, stream>>>(qws, kws, vtws, yws);
  gemm_kernel<1><<<dim3(64, 4), dim3(512), 0, stream>>>(yws, wpT, bp, nullptr, nullptr, nullptr, out);
}

// Round 11
// 182.314 us; speedup vs baseline: 2.1090x; 1.0730x over previous
//
#include <hip/hip_runtime.h>
#include <hip/hip_bf16.h>
#include <stdint.h>

// Fused causal self-attention block: qkv GEMM -> flash attention -> proj GEMM.
// B=4 T=2048 E=1024 H=16 HD=64. All matmuls bf16 MFMA, fp32 accumulate.
// GEMMs: 128x256 tile, BK=64, 8 waves, 3-buf pipeline, ONE barrier + ONE
// counted vmcnt(6) per K-tile (32 MFMA between barriers), slot-XOR LDS
// swizzle both-sides (T2/T21), setprio (T5), coalesced V^T epilogue via LDS
// (scratch stored TRANSPOSED [d][t] so b128 reads along t are contiguous —
// R10's bug was [t][d] scratch read as [d][t]).
// Attention: 32x32 swapped-QK (mfma(K,Q)) with fully in-register softmax.

#define B_  4
#define T_  2048
#define E_  1024
#define H_  16
#define HD_ 64

typedef unsigned short u16;
typedef __bf16 bf16x8 __attribute__((ext_vector_type(8)));
typedef float f32x4 __attribute__((ext_vector_type(4)));
typedef float f32x16 __attribute__((ext_vector_type(16)));

struct alignas(8) us4 { u16 x, y, z, w; };

// native bf16 convert (compiler emits v_cvt_pk_bf16_f32; RNE)
__device__ __forceinline__ u16 tobf(float f) {
  union { __bf16 h; u16 u; } c;
  c.h = (__bf16)f;
  return c.u;
}

__device__ __forceinline__ void gload_lds16(const void* g, void* l) {
  // global -> LDS direct, 16B/lane (wave-uniform LDS base + lane*16).
  auto gp = reinterpret_cast<const __attribute__((address_space(1))) uint32_t*>(
      reinterpret_cast<uintptr_t>(g));
  auto lp = reinterpret_cast<__attribute__((address_space(3))) uint32_t*>(
      reinterpret_cast<uintptr_t>(l));
  __builtin_amdgcn_global_load_lds(gp, lp, 16, 0, 0);
}

__device__ __forceinline__ bf16x8 ld_frag(const u16* p) {
  return *reinterpret_cast<const bf16x8*>(p);
}

// raw barrier + compiler memory fence (NOT __syncthreads: that drains vmcnt(0)
// and kills the counted-vmcnt pipeline)
#define BARRIER() do { __builtin_amdgcn_s_barrier(); asm volatile("" ::: "memory"); } while (0)

// ---------------- conversion kernels ----------------

__global__ void cvt_bf16_kernel(const float* __restrict__ in, u16* __restrict__ out, int n) {
  int i = (blockIdx.x * blockDim.x + threadIdx.x) * 4;
  if (i >= n) return;
  float4 v = *reinterpret_cast<const float4*>(in + i);
  us4 o = { tobf(v.x), tobf(v.y), tobf(v.z), tobf(v.w) };
  *reinterpret_cast<us4*>(out + i) = o;
}

// in: [K][N] f32 row-major -> out: [N][K] bf16 (B^T layout for GEMM)
__global__ void transpose_cvt_kernel(const float* __restrict__ in, u16* __restrict__ out,
                                     int K, int N) {
  __shared__ u16 tile[32][33];
  int n0 = blockIdx.x * 32, k0 = blockIdx.y * 32;
  int tx = threadIdx.x, ty = threadIdx.y;  // (32,8)
#pragma unroll
  for (int i = 0; i < 32; i += 8)
    tile[ty + i][tx] = tobf(in[(size_t)(k0 + ty + i) * N + n0 + tx]);
  __syncthreads();
#pragma unroll
  for (int i = 0; i < 32; i += 8)
    out[(size_t)(n0 + ty + i) * K + k0 + tx] = tile[tx][ty + i];
}

// ---------------- GEMM: 128x256, BK=64, 8 waves, 3-buf, 1 barrier/K-tile ---

template <int MODE>
__launch_bounds__(512, 2)
__global__ void gemm_kernel(const u16* __restrict__ A, const u16* __restrict__ Bt,
                            const float* __restrict__ bias,
                            u16* __restrict__ qws, u16* __restrict__ kws,
                            u16* __restrict__ vtws, float* __restrict__ out) {
  constexpr int K = 1024, NT = 16;     // 16 K-tiles of 64
  __shared__ u16 Asm[3 * 8192];        // 3 bufs x 128x64  (48KB)
  __shared__ u16 Bsm[3 * 16384];       // 3 bufs x 256x64  (96KB)
  const int tid = threadIdx.x;
  const int wid = tid >> 6, lane = tid & 63;
  const int wm = wid >> 2, wn = wid & 3;     // 2M x 4N waves; 64x64 out/wave
  const int row0 = blockIdx.x * 128, col0 = blockIdx.y * 256;

  // staging: issue j covers rows j*64 + wid*8 + (lane>>3); slot = lane&7.
  // LDS[row][slot] = G[row][slot ^ (row&7)] -> source slot pre-XORed.
  const int sgrow = wid * 8 + (lane >> 3);
  const int sgslot = (lane & 7) ^ (lane >> 3);
  // read-side: frag (x,kk): row = x*16+lrow, LDS slot = (kk*4+lks) ^ (lrow&7)
  const int lrow = lane & 15, lks = lane >> 4, r7 = lrow & 7;
  const int ca0 = ((lks) ^ r7) * 8;          // kk=0 col offset (u16)
  const int ca1 = ((4 + lks) ^ r7) * 8;      // kk=1
  const int bhalf = (wn >> 1) * 8192 + (wn & 1) * 4096;

#define STG_A(sb, kt, j)                                                        \
  gload_lds16(A + (size_t)(row0 + (j) * 64 + sgrow) * K + (kt) * 64 + sgslot * 8, \
              &Asm[(sb) * 8192 + (j) * 4096 + wid * 512])
#define STG_B(sb, kt, h, j)                                                     \
  gload_lds16(Bt + (size_t)(col0 + (h) * 128 + (j) * 64 + sgrow) * K + (kt) * 64 + sgslot * 8, \
              &Bsm[(sb) * 16384 + (h) * 8192 + (j) * 4096 + wid * 512])
#define RDA(mi, cc) ld_frag(&Asm[rb * 8192 + (wm * 64 + (mi) * 16 + lrow) * 64 + (cc)])
#define RDB(ni, cc) ld_frag(&Bsm[rb * 16384 + bhalf + ((ni) * 16 + lrow) * 64 + (cc)])

  f32x4 acc[4][4] = {};

  // prologue: stage K-tiles 0 (buf 0) and 1 (buf 1), 6 loads each, in order
  STG_A(0, 0, 0); STG_A(0, 0, 1);
  STG_B(0, 0, 0, 0); STG_B(0, 0, 0, 1); STG_B(0, 0, 1, 0); STG_B(0, 0, 1, 1);
  STG_A(1, 1, 0); STG_A(1, 1, 1);
  STG_B(1, 1, 0, 0); STG_B(1, 1, 0, 1); STG_B(1, 1, 1, 0); STG_B(1, 1, 1, 1);
  asm volatile("s_waitcnt vmcnt(6)" ::: "memory");  // tile 0's 6 landed
  BARRIER();

  for (int t = 0; t < NT; ++t) {
    const int rb = t % 3;
    const int sb = (t + 2) % 3;       // buffer of tile t+2 (freed at end of t-1)
    const bool hs = (t + 2) < NT;
    const int kt = t + 2;
    bf16x8 af[4], bf[4];

    // kk=0 frags + stage A(t+2)
    af[0] = RDA(0, ca0); af[1] = RDA(1, ca0); af[2] = RDA(2, ca0); af[3] = RDA(3, ca0);
    bf[0] = RDB(0, ca0); bf[1] = RDB(1, ca0); bf[2] = RDB(2, ca0); bf[3] = RDB(3, ca0);
    if (hs) { STG_A(sb, kt, 0); STG_A(sb, kt, 1); }
    __builtin_amdgcn_s_setprio(1);
#pragma unroll
    for (int mi = 0; mi < 4; ++mi)
#pragma unroll
      for (int ni = 0; ni < 4; ++ni)
        acc[mi][ni] = __builtin_amdgcn_mfma_f32_16x16x32_bf16(af[mi], bf[ni], acc[mi][ni], 0, 0, 0);
    __builtin_amdgcn_s_setprio(0);

    // kk=1 frags + stage B(t+2)
    af[0] = RDA(0, ca1); af[1] = RDA(1, ca1); af[2] = RDA(2, ca1); af[3] = RDA(3, ca1);
    bf[0] = RDB(0, ca1); bf[1] = RDB(1, ca1); bf[2] = RDB(2, ca1); bf[3] = RDB(3, ca1);
    if (hs) { STG_B(sb, kt, 0, 0); STG_B(sb, kt, 0, 1); STG_B(sb, kt, 1, 0); STG_B(sb, kt, 1, 1); }
    __builtin_amdgcn_s_setprio(1);
#pragma unroll
    for (int mi = 0; mi < 4; ++mi)
#pragma unroll
      for (int ni = 0; ni < 4; ++ni)
        acc[mi][ni] = __builtin_amdgcn_mfma_f32_16x16x32_bf16(af[mi], bf[ni], acc[mi][ni], 0, 0, 0);
    __builtin_amdgcn_s_setprio(0);

    // drain tile t+1's stages (issued during t-1); leave this tile's 6 in flight
    if (hs) asm volatile("s_waitcnt vmcnt(6)" ::: "memory");
    else    asm volatile("s_waitcnt vmcnt(0)" ::: "memory");
    BARRIER();  // publishes stages for t+1 AND fences re-staging of rb(t) by t+1
  }
#undef STG_A
#undef STG_B
#undef RDA
#undef RDB

  // C/D layout: col = lane&15, row = (lane>>4)*4 + reg
  if constexpr (MODE == 0) {
    const int part = (col0 + wn * 64) >> 10;    // wave-uniform: 0=q 1=k 2=v
    if (part < 2) {
#pragma unroll
      for (int mi = 0; mi < 4; ++mi) {
#pragma unroll
        for (int ni = 0; ni < 4; ++ni) {
          const int gr0 = row0 + wm * 64 + mi * 16 + (lane >> 4) * 4;
          const int gc = col0 + wn * 64 + ni * 16 + (lane & 15);
          const float bv = bias[gc];
          const int e = gc & 1023;
          const int h = e >> 6, d = e & 63;
#pragma unroll
          for (int r = 0; r < 4; ++r) {
            const int m = gr0 + r;
            const int b = m >> 11, tt = m & 2047;
            const float val = acc[mi][ni][r] + bv;
            const size_t bh = (size_t)(b * H_ + h);
            if (part == 0)
              // fold 1/sqrt(64) * log2(e): softmax done in exp2 domain
              qws[(bh * T_ + tt) * HD_ + d] = tobf(val * 0.1803368801f);
            else
              kws[(bh * T_ + tt) * HD_ + d] = tobf(val);
          }
        }
      }
    } else {
      // V: transpose via per-wave LDS scratch stored [d_local][t_local]
      // (rows padded to 72 u16), then 8 coalesced b128 stores along T.
      u16* vt_l = &Bsm[wid * 4608];
#pragma unroll
      for (int mi = 0; mi < 4; ++mi)
#pragma unroll
        for (int ni = 0; ni < 4; ++ni) {
          const float bv = bias[col0 + wn * 64 + ni * 16 + (lane & 15)];
#pragma unroll
          for (int r = 0; r < 4; ++r)
            vt_l[(ni * 16 + (lane & 15)) * 72 + mi * 16 + (lane >> 4) * 4 + r] =
                tobf(acc[mi][ni][r] + bv);
        }
      const int e0 = col0 + wn * 64 - 2048;   // multiple of 64 -> one full head
      const int h = e0 >> 6;
      const int m0 = row0 + wm * 64;
      const int b = m0 >> 11, tbase = m0 & 2047;
      u16* vbase = vtws + (size_t)(b * H_ + h) * HD_ * T_;
#pragma unroll
      for (int it = 0; it < 8; ++it) {
        const int d = it * 8 + (lane >> 3);
        const uint4 vv = *reinterpret_cast<const uint4*>(&vt_l[d * 72 + (lane & 7) * 8]);
        *reinterpret_cast<uint4*>(&vbase[(size_t)d * T_ + tbase + (lane & 7) * 8]) = vv;
      }
    }
  } else {
#pragma unroll
    for (int mi = 0; mi < 4; ++mi) {
#pragma unroll
      for (int ni = 0; ni < 4; ++ni) {
        const int gr0 = row0 + wm * 64 + mi * 16 + (lane >> 4) * 4;
        const int gc = col0 + wn * 64 + ni * 16 + (lane & 15);
        const float bv = bias[gc];
#pragma unroll
        for (int r = 0; r < 4; ++r)
          out[(size_t)(gr0 + r) * E_ + gc] = acc[mi][ni][r] + bv;
      }
    }
  }
}

// ---------------- flash attention (32x32 swapped-QK, in-register softmax) ---
// grid = 1024 blocks x 256 threads (4 waves). LPT dispatch: j = 15-(bid>>6)
// (longest Q-tiles first, short ones backfill the tail); bh = bid&63 pins
// head to XCD (8 heads x 512KB = 4MB per L2). Wave owns 32 q rows. QK^T
// swapped (A=K, B=Q, 32x32x16): lane holds a full q-row -> softmax in-lane +
// one shfl_xor(32). P redistributed to PV A-frags in-register (no LDS
// roundtrip). K/V tiles (32 kv) reg-staged to LDS, padded rows, dbuf.

__launch_bounds__(256, 4)
__global__ void attn_kernel(const u16* __restrict__ q, const u16* __restrict__ k,
                            const u16* __restrict__ vt, u16* __restrict__ y) {
  __shared__ u16 kl[2][32 * 68];   // K tile: 32 kv rows x 64 hd, rows padded to 136B
  __shared__ u16 vl[2][64 * 36];   // V^T tile: 64 d rows x 32 kv, rows padded to 72B
  const int tid = threadIdx.x, w = tid >> 6, lane = tid & 63;
  const int l31 = lane & 31, hi = lane >> 5;
  const bool H = hi != 0;
  const int bid = blockIdx.x;
  const int j = 15 - (bid >> 6);           // LPT: longest first
  const int bh = bid & 63;
  const u16* qp = q + (size_t)bh * T_ * HD_;
  const u16* kp = k + (size_t)bh * T_ * HD_;
  const u16* vp = vt + (size_t)bh * HD_ * T_;
  const int b = bh >> 4, h = bh & 15;
  u16* yb = y + (size_t)b * T_ * E_ + h * HD_;

  const int t0 = j * 128;
  const int qbw = t0 + w * 32;          // wave's first q row
  const int nblk = (t0 + 128) >> 5;     // 32-kv tiles

  // Q fragments (B-operand): lane holds Q[qbw + l31][slot*16 + hi*8 + e]
  bf16x8 aq[4];
#pragma unroll
  for (int slot = 0; slot < 4; ++slot)
    aq[slot] = ld_frag(qp + (size_t)(qbw + l31) * HD_ + slot * 16 + hi * 8);

  f32x16 o0 = {}, o1 = {};              // O[q=crow(r,hi)][d = dt*32 + l31]
  float mr = -1e30f, lr = 0.f;          // stats for row q = l31 (lane-local)

  // staging assignments
  const int skv = w * 8 + (lane >> 3);  // K: 8 rows/wave, 8 lanes x 16B per row
  const int skc = (lane & 7) * 8;
  const int svd = w * 16 + (lane >> 2); // V: 16 rows/wave, 4 lanes x 16B per row
  const int svc = (lane & 3) * 8;

  uint4 kreg = *(const uint4*)(kp + (size_t)skv * HD_ + skc);
  uint4 vreg = *(const uint4*)(vp + (size_t)svd * T_ + svc);

  int buf = 0;
  for (int kb = 0; kb < nblk; ++kb) {
    const int kv0 = kb * 32;
    // write staged tile to LDS (2x b64 each; padded rows)
    {
      u16* kd = &kl[buf][skv * 68 + skc];
      uint2 ka = {kreg.x, kreg.y}, kb2 = {kreg.z, kreg.w};
      *(uint2*)kd = ka;
      *(uint2*)(kd + 4) = kb2;
      u16* vd = &vl[buf][svd * 36 + svc];
      uint2 va = {vreg.x, vreg.y}, vb2 = {vreg.z, vreg.w};
      *(uint2*)vd = va;
      *(uint2*)(vd + 4) = vb2;
    }
    // issue next tile's global loads (latency hides under compute — T14)
    if (kb + 1 < nblk) {
      const int kvn = kv0 + 32;
      kreg = *(const uint4*)(kp + (size_t)(kvn + skv) * HD_ + skc);
      vreg = *(const uint4*)(vp + (size_t)svd * T_ + kvn + svc);
    }
    __syncthreads();

    if (kv0 <= qbw + 31) {              // wave-uniform causal skip
      // S = K·Q^T (swapped): lane holds 16 kv values of q-row l31.
      f32x16 s = {};
      __builtin_amdgcn_s_setprio(1);
#pragma unroll
      for (int slot = 0; slot < 4; ++slot) {
        union { uint2 d[2]; bf16x8 v; } kf;
        const u16* kr = &kl[buf][l31 * 68 + slot * 16 + hi * 8];
        kf.d[0] = *(const uint2*)kr;
        kf.d[1] = *(const uint2*)(kr + 4);
        s = __builtin_amdgcn_mfma_f32_32x32x16_bf16(kf.v, aq[slot], s, 0, 0, 0);
      }
      __builtin_amdgcn_s_setprio(0);

      // causal mask: kv = kv0 + crow(r,hi), q = qbw + l31
      if (kv0 + 31 > qbw) {
        const int qq = qbw + l31;
#pragma unroll
        for (int r = 0; r < 16; ++r) {
          const int kv = kv0 + (r & 3) + 8 * (r >> 2) + 4 * hi;
          if (kv > qq) s[r] = -1e30f;
        }
      }

      // row max: in-lane tree + partner half
      float t[8];
#pragma unroll
      for (int r = 0; r < 8; ++r) t[r] = fmaxf(s[r], s[r + 8]);
#pragma unroll
      for (int r = 0; r < 4; ++r) t[r] = fmaxf(t[r], t[r + 4]);
      float pm = fmaxf(fmaxf(t[0], t[1]), fmaxf(t[2], t[3]));
      pm = fmaxf(pm, __shfl_xor(pm, 32));

      // deferred rescale (T13)
      if (__any(pm > mr + 8.f)) {
        const float mn = fmaxf(mr, pm);
        const float al = exp2f(mr - mn);
        mr = mn;
        lr *= al;
#pragma unroll
        for (int r = 0; r < 16; ++r) {
          const float ab = __shfl(al, ((r & 3) + 8 * (r >> 2) + 4 * hi) + (lane & 32));
          o0[r] *= ab;
          o1[r] *= ab;
        }
      }

      // P = exp2(S - mr), row sum
      float p[16];
      float rs = 0.f;
#pragma unroll
      for (int r = 0; r < 16; ++r) {
        p[r] = exp2f(s[r] - mr);
        rs += p[r];
      }
      rs += __shfl_xor(rs, 32);
      lr += rs;

      // pack P to bf16 pairs; redistribute to PV A-fragments in-register.
      unsigned cw[8];
#pragma unroll
      for (int i = 0; i < 8; ++i) {
        union { __bf16 hh[2]; unsigned u; } pk;
        pk.hh[0] = (__bf16)p[2 * i];
        pk.hh[1] = (__bf16)p[2 * i + 1];
        cw[i] = pk.u;
      }
      const unsigned r0 = __shfl_xor(H ? cw[0] : cw[2], 32);
      const unsigned r1 = __shfl_xor(H ? cw[1] : cw[3], 32);
      const unsigned r2 = __shfl_xor(H ? cw[4] : cw[6], 32);
      const unsigned r3 = __shfl_xor(H ? cw[5] : cw[7], 32);
      union PU { unsigned u[4]; bf16x8 v; } pa0, pa1;
      pa0.u[0] = H ? r0 : cw[0];
      pa0.u[1] = H ? r1 : cw[1];
      pa0.u[2] = H ? cw[2] : r0;
      pa0.u[3] = H ? cw[3] : r1;
      pa1.u[0] = H ? r2 : cw[4];
      pa1.u[1] = H ? r3 : cw[5];
      pa1.u[2] = H ? cw[6] : r2;
      pa1.u[3] = H ? cw[7] : r3;

      // O += P·V : B-frags from vl rows d = dt*32 + l31, k = ks*16 + hi*8 + e
      __builtin_amdgcn_s_setprio(1);
      {
        union { uint2 d[2]; bf16x8 v; } vf;
        const u16* vr0 = &vl[buf][l31 * 36 + hi * 8];
        vf.d[0] = *(const uint2*)vr0;
        vf.d[1] = *(const uint2*)(vr0 + 4);
        o0 = __builtin_amdgcn_mfma_f32_32x32x16_bf16(pa0.v, vf.v, o0, 0, 0, 0);
        vf.d[0] = *(const uint2*)(vr0 + 16);
        vf.d[1] = *(const uint2*)(vr0 + 20);
        o0 = __builtin_amdgcn_mfma_f32_32x32x16_bf16(pa1.v, vf.v, o0, 0, 0, 0);
        const u16* vr1 = &vl[buf][(32 + l31) * 36 + hi * 8];
        vf.d[0] = *(const uint2*)vr1;
        vf.d[1] = *(const uint2*)(vr1 + 4);
        o1 = __builtin_amdgcn_mfma_f32_32x32x16_bf16(pa0.v, vf.v, o1, 0, 0, 0);
        vf.d[0] = *(const uint2*)(vr1 + 16);
        vf.d[1] = *(const uint2*)(vr1 + 20);
        o1 = __builtin_amdgcn_mfma_f32_32x32x16_bf16(pa1.v, vf.v, o1, 0, 0, 0);
      }
      __builtin_amdgcn_s_setprio(0);
    }
    buf ^= 1;
  }

  // normalize + write: O row q=crow(r,hi) needs 1/lr from lane q (|32 half)
  const float il = 1.f / lr;
#pragma unroll
  for (int r = 0; r < 16; ++r) {
    const int cr = (r & 3) + 8 * (r >> 2) + 4 * hi;
    const float li = __shfl(il, cr + (lane & 32));
    const size_t row = (size_t)(qbw + cr) * E_;
    yb[row + l31] = tobf(o0[r] * li);
    yb[row + 32 + l31] = tobf(o1[r] * li);
  }
}

// ---------------- launch ----------------

extern "C" void kernel_launch(void* const* d_in, const int* in_sizes, int n_in,
                              void* d_out, int out_size, void* d_ws, size_t ws_size,
                              hipStream_t stream) {
  const float* x  = (const float*)d_in[0];
  const float* Wa = (const float*)d_in[1];
  const float* ba = (const float*)d_in[2];
  const float* Wp = (const float*)d_in[3];
  const float* bp = (const float*)d_in[4];
  float* out = (float*)d_out;

  u16* ws   = (u16*)d_ws;
  u16* xb   = ws;                                  // 8M  (x bf16; later y bf16)
  u16* waT  = xb  + (size_t)8 * 1024 * 1024;       // 3M  (W_attn^T bf16)
  u16* wpT  = waT + (size_t)3 * 1024 * 1024;       // 1M  (W_proj^T bf16)
  u16* qws  = wpT + (size_t)1024 * 1024;           // 8M  q [B,H,T,HD]
  u16* kws  = qws + (size_t)8 * 1024 * 1024;       // 8M  k [B,H,T,HD]
  u16* vtws = kws + (size_t)8 * 1024 * 1024;       // 8M  v^T [B,H,HD,T]
  u16* yws  = xb;                                  // alias

  cvt_bf16_kernel<<<dim3(8192), dim3(256), 0, stream>>>(x, xb, 8 * 1024 * 1024);
  transpose_cvt_kernel<<<dim3(96, 32), dim3(32, 8), 0, stream>>>(Wa, waT, 1024, 3072);
  transpose_cvt_kernel<<<dim3(32, 32), dim3(32, 8), 0, stream>>>(Wp, wpT, 1024, 1024);

  gemm_kernel<0><<<dim3(64, 12), dim3(512), 0, stream>>>(xb, waT, ba, qws, kws, vtws, nullptr);
  attn_kernel<<<dim3(1024), dim3(256), 0, stream>>>(qws, kws, vtws, yws);
  gemm_kernel<1><<<dim3(64, 4), dim3(512), 0, stream>>>(yws, wpT, bp, nullptr, nullptr, nullptr, out);
}

// Round 12
// 177.539 us; speedup vs baseline: 2.1658x; 1.0269x over previous
//
#include <hip/hip_runtime.h>
#include <hip/hip_bf16.h>
#include <stdint.h>

// Fused causal self-attention block: qkv GEMM -> flash attention -> proj GEMM.
// B=4 T=2048 E=1024 H=16 HD=64. All matmuls bf16 MFMA, fp32 accumulate.
// GEMMs: 128x256 tile, BK=64, 8 waves, 3-buf pipeline, ONE barrier + ONE
// counted vmcnt(6) per K-tile (32 MFMA between barriers), slot-XOR LDS
// swizzle both-sides (T2/T21), setprio (T5), coalesced V^T epilogue via LDS.
// Attention: 32x32 swapped-QK (mfma(K,Q)) with fully in-register softmax;
// 64-kv staging passes (2 compute rounds/pass); CU-balanced LPT tile map.

#define B_  4
#define T_  2048
#define E_  1024
#define H_  16
#define HD_ 64

typedef unsigned short u16;
typedef __bf16 bf16x8 __attribute__((ext_vector_type(8)));
typedef float f32x4 __attribute__((ext_vector_type(4)));
typedef float f32x16 __attribute__((ext_vector_type(16)));

struct alignas(8) us4 { u16 x, y, z, w; };

// native bf16 convert (compiler emits v_cvt_pk_bf16_f32; RNE)
__device__ __forceinline__ u16 tobf(float f) {
  union { __bf16 h; u16 u; } c;
  c.h = (__bf16)f;
  return c.u;
}

__device__ __forceinline__ void gload_lds16(const void* g, void* l) {
  // global -> LDS direct, 16B/lane (wave-uniform LDS base + lane*16).
  auto gp = reinterpret_cast<const __attribute__((address_space(1))) uint32_t*>(
      reinterpret_cast<uintptr_t>(g));
  auto lp = reinterpret_cast<__attribute__((address_space(3))) uint32_t*>(
      reinterpret_cast<uintptr_t>(l));
  __builtin_amdgcn_global_load_lds(gp, lp, 16, 0, 0);
}

__device__ __forceinline__ bf16x8 ld_frag(const u16* p) {
  return *reinterpret_cast<const bf16x8*>(p);
}

// raw barrier + compiler memory fence (NOT __syncthreads: that drains vmcnt(0)
// and kills the counted-vmcnt pipeline)
#define BARRIER() do { __builtin_amdgcn_s_barrier(); asm volatile("" ::: "memory"); } while (0)

// ---------------- conversion kernels ----------------

__global__ void cvt_bf16_kernel(const float* __restrict__ in, u16* __restrict__ out, int n) {
  int i = (blockIdx.x * blockDim.x + threadIdx.x) * 4;
  if (i >= n) return;
  float4 v = *reinterpret_cast<const float4*>(in + i);
  us4 o = { tobf(v.x), tobf(v.y), tobf(v.z), tobf(v.w) };
  *reinterpret_cast<us4*>(out + i) = o;
}

// in: [K][N] f32 row-major -> out: [N][K] bf16 (B^T layout for GEMM)
__global__ void transpose_cvt_kernel(const float* __restrict__ in, u16* __restrict__ out,
                                     int K, int N) {
  __shared__ u16 tile[32][33];
  int n0 = blockIdx.x * 32, k0 = blockIdx.y * 32;
  int tx = threadIdx.x, ty = threadIdx.y;  // (32,8)
#pragma unroll
  for (int i = 0; i < 32; i += 8)
    tile[ty + i][tx] = tobf(in[(size_t)(k0 + ty + i) * N + n0 + tx]);
  __syncthreads();
#pragma unroll
  for (int i = 0; i < 32; i += 8)
    out[(size_t)(n0 + ty + i) * K + k0 + tx] = tile[tx][ty + i];
}

// ---------------- GEMM: 128x256, BK=64, 8 waves, 3-buf, 1 barrier/K-tile ---

template <int MODE>
__launch_bounds__(512, 2)
__global__ void gemm_kernel(const u16* __restrict__ A, const u16* __restrict__ Bt,
                            const float* __restrict__ bias,
                            u16* __restrict__ qws, u16* __restrict__ kws,
                            u16* __restrict__ vtws, float* __restrict__ out) {
  constexpr int K = 1024, NT = 16;     // 16 K-tiles of 64
  __shared__ u16 Asm[3 * 8192];        // 3 bufs x 128x64  (48KB)
  __shared__ u16 Bsm[3 * 16384];       // 3 bufs x 256x64  (96KB)
  const int tid = threadIdx.x;
  const int wid = tid >> 6, lane = tid & 63;
  const int wm = wid >> 2, wn = wid & 3;     // 2M x 4N waves; 64x64 out/wave
  const int row0 = blockIdx.x * 128, col0 = blockIdx.y * 256;

  const int sgrow = wid * 8 + (lane >> 3);
  const int sgslot = (lane & 7) ^ (lane >> 3);
  const int lrow = lane & 15, lks = lane >> 4, r7 = lrow & 7;
  const int ca0 = ((lks) ^ r7) * 8;          // kk=0 col offset (u16)
  const int ca1 = ((4 + lks) ^ r7) * 8;      // kk=1
  const int bhalf = (wn >> 1) * 8192 + (wn & 1) * 4096;

#define STG_A(sb, kt, j)                                                        \
  gload_lds16(A + (size_t)(row0 + (j) * 64 + sgrow) * K + (kt) * 64 + sgslot * 8, \
              &Asm[(sb) * 8192 + (j) * 4096 + wid * 512])
#define STG_B(sb, kt, h, j)                                                     \
  gload_lds16(Bt + (size_t)(col0 + (h) * 128 + (j) * 64 + sgrow) * K + (kt) * 64 + sgslot * 8, \
              &Bsm[(sb) * 16384 + (h) * 8192 + (j) * 4096 + wid * 512])
#define RDA(mi, cc) ld_frag(&Asm[rb * 8192 + (wm * 64 + (mi) * 16 + lrow) * 64 + (cc)])
#define RDB(ni, cc) ld_frag(&Bsm[rb * 16384 + bhalf + ((ni) * 16 + lrow) * 64 + (cc)])

  f32x4 acc[4][4] = {};

  // prologue: stage K-tiles 0 (buf 0) and 1 (buf 1), 6 loads each, in order
  STG_A(0, 0, 0); STG_A(0, 0, 1);
  STG_B(0, 0, 0, 0); STG_B(0, 0, 0, 1); STG_B(0, 0, 1, 0); STG_B(0, 0, 1, 1);
  STG_A(1, 1, 0); STG_A(1, 1, 1);
  STG_B(1, 1, 0, 0); STG_B(1, 1, 0, 1); STG_B(1, 1, 1, 0); STG_B(1, 1, 1, 1);
  asm volatile("s_waitcnt vmcnt(6)" ::: "memory");  // tile 0's 6 landed
  BARRIER();

  for (int t = 0; t < NT; ++t) {
    const int rb = t % 3;
    const int sb = (t + 2) % 3;       // buffer of tile t+2 (freed at end of t-1)
    const bool hs = (t + 2) < NT;
    const int kt = t + 2;
    bf16x8 af[4], bf[4];

    // kk=0 frags + stage A(t+2)
    af[0] = RDA(0, ca0); af[1] = RDA(1, ca0); af[2] = RDA(2, ca0); af[3] = RDA(3, ca0);
    bf[0] = RDB(0, ca0); bf[1] = RDB(1, ca0); bf[2] = RDB(2, ca0); bf[3] = RDB(3, ca0);
    if (hs) { STG_A(sb, kt, 0); STG_A(sb, kt, 1); }
    __builtin_amdgcn_s_setprio(1);
#pragma unroll
    for (int mi = 0; mi < 4; ++mi)
#pragma unroll
      for (int ni = 0; ni < 4; ++ni)
        acc[mi][ni] = __builtin_amdgcn_mfma_f32_16x16x32_bf16(af[mi], bf[ni], acc[mi][ni], 0, 0, 0);
    __builtin_amdgcn_s_setprio(0);

    // kk=1 frags + stage B(t+2)
    af[0] = RDA(0, ca1); af[1] = RDA(1, ca1); af[2] = RDA(2, ca1); af[3] = RDA(3, ca1);
    bf[0] = RDB(0, ca1); bf[1] = RDB(1, ca1); bf[2] = RDB(2, ca1); bf[3] = RDB(3, ca1);
    if (hs) { STG_B(sb, kt, 0, 0); STG_B(sb, kt, 0, 1); STG_B(sb, kt, 1, 0); STG_B(sb, kt, 1, 1); }
    __builtin_amdgcn_s_setprio(1);
#pragma unroll
    for (int mi = 0; mi < 4; ++mi)
#pragma unroll
      for (int ni = 0; ni < 4; ++ni)
        acc[mi][ni] = __builtin_amdgcn_mfma_f32_16x16x32_bf16(af[mi], bf[ni], acc[mi][ni], 0, 0, 0);
    __builtin_amdgcn_s_setprio(0);

    // drain tile t+1's stages (issued during t-1); leave this tile's 6 in flight
    if (hs) asm volatile("s_waitcnt vmcnt(6)" ::: "memory");
    else    asm volatile("s_waitcnt vmcnt(0)" ::: "memory");
    BARRIER();  // publishes stages for t+1 AND fences re-staging of rb(t) by t+1
  }
#undef STG_A
#undef STG_B
#undef RDA
#undef RDB

  // C/D layout: col = lane&15, row = (lane>>4)*4 + reg
  if constexpr (MODE == 0) {
    const int part = (col0 + wn * 64) >> 10;    // wave-uniform: 0=q 1=k 2=v
    if (part < 2) {
#pragma unroll
      for (int mi = 0; mi < 4; ++mi) {
#pragma unroll
        for (int ni = 0; ni < 4; ++ni) {
          const int gr0 = row0 + wm * 64 + mi * 16 + (lane >> 4) * 4;
          const int gc = col0 + wn * 64 + ni * 16 + (lane & 15);
          const float bv = bias[gc];
          const int e = gc & 1023;
          const int h = e >> 6, d = e & 63;
#pragma unroll
          for (int r = 0; r < 4; ++r) {
            const int m = gr0 + r;
            const int b = m >> 11, tt = m & 2047;
            const float val = acc[mi][ni][r] + bv;
            const size_t bh = (size_t)(b * H_ + h);
            if (part == 0)
              // fold 1/sqrt(64) * log2(e): softmax done in exp2 domain
              qws[(bh * T_ + tt) * HD_ + d] = tobf(val * 0.1803368801f);
            else
              kws[(bh * T_ + tt) * HD_ + d] = tobf(val);
          }
        }
      }
    } else {
      // V: transpose via per-wave LDS scratch stored [d_local][t_local]
      // (rows padded to 72 u16), then 8 coalesced b128 stores along T.
      u16* vt_l = &Bsm[wid * 4608];
#pragma unroll
      for (int mi = 0; mi < 4; ++mi)
#pragma unroll
        for (int ni = 0; ni < 4; ++ni) {
          const float bv = bias[col0 + wn * 64 + ni * 16 + (lane & 15)];
#pragma unroll
          for (int r = 0; r < 4; ++r)
            vt_l[(ni * 16 + (lane & 15)) * 72 + mi * 16 + (lane >> 4) * 4 + r] =
                tobf(acc[mi][ni][r] + bv);
        }
      const int e0 = col0 + wn * 64 - 2048;   // multiple of 64 -> one full head
      const int h = e0 >> 6;
      const int m0 = row0 + wm * 64;
      const int b = m0 >> 11, tbase = m0 & 2047;
      u16* vbase = vtws + (size_t)(b * H_ + h) * HD_ * T_;
#pragma unroll
      for (int it = 0; it < 8; ++it) {
        const int d = it * 8 + (lane >> 3);
        const uint4 vv = *reinterpret_cast<const uint4*>(&vt_l[d * 72 + (lane & 7) * 8]);
        *reinterpret_cast<uint4*>(&vbase[(size_t)d * T_ + tbase + (lane & 7) * 8]) = vv;
      }
    }
  } else {
#pragma unroll
    for (int mi = 0; mi < 4; ++mi) {
#pragma unroll
      for (int ni = 0; ni < 4; ++ni) {
        const int gr0 = row0 + wm * 64 + mi * 16 + (lane >> 4) * 4;
        const int gc = col0 + wn * 64 + ni * 16 + (lane & 15);
        const float bv = bias[gc];
#pragma unroll
        for (int r = 0; r < 4; ++r)
          out[(size_t)(gr0 + r) * E_ + gc] = acc[mi][ni][r] + bv;
      }
    }
  }
}

// ---------------- flash attention (32x32 swapped-QK, in-register softmax) ---
// grid = 1024 blocks x 256 threads (4 waves). CU-balanced LPT map: with
// s=bid>>8, a=(bid>>6)&3, j = {15-a, 8+a, 7-a, a}[s] -> every CU's 4 blocks
// sum to 30 work units (was 24-36); long tiles dispatch first; bh=bid&63
// keeps heads XCD-pinned. Wave owns 32 q rows. QK^T swapped (A=K, B=Q,
// 32x32x16): lane holds a full q-row -> softmax in-lane + one shfl_xor(32).
// P redistributed to PV A-frags in-register. K/V staged at 64-kv granularity
// (2 compute rounds per staged pass -> half the barriers/staging issues),
// reg-staged (T14), padded rows, dbuf. Defer-max (T13); setprio (T5).

__launch_bounds__(256, 4)
__global__ void attn_kernel(const u16* __restrict__ q, const u16* __restrict__ k,
                            const u16* __restrict__ vt, u16* __restrict__ y) {
  __shared__ u16 kl[2][64 * 68];   // K: 64 kv rows x 64 hd, rows padded to 136B
  __shared__ u16 vl[2][64 * 68];   // V^T: 64 d rows x 64 kv, rows padded to 136B
  const int tid = threadIdx.x, w = tid >> 6, lane = tid & 63;
  const int l31 = lane & 31, hi = lane >> 5;
  const bool H = hi != 0;
  const int bid = blockIdx.x;
  const int s4 = bid >> 8, a = (bid >> 6) & 3;
  const int j = (s4 == 0) ? (15 - a) : (s4 == 1) ? (8 + a) : (s4 == 2) ? (7 - a) : a;
  const int bh = bid & 63;
  const u16* qp = q + (size_t)bh * T_ * HD_;
  const u16* kp = k + (size_t)bh * T_ * HD_;
  const u16* vp = vt + (size_t)bh * HD_ * T_;
  const int b = bh >> 4, h = bh & 15;
  u16* yb = y + (size_t)b * T_ * E_ + h * HD_;

  const int t0 = j * 128;
  const int qbw = t0 + w * 32;          // wave's first q row
  const int npass = (t0 + 128) >> 6;    // 64-kv staging passes

  // Q fragments (B-operand): lane holds Q[qbw + l31][slot*16 + hi*8 + e]
  bf16x8 aq[4];
#pragma unroll
  for (int slot = 0; slot < 4; ++slot)
    aq[slot] = ld_frag(qp + (size_t)(qbw + l31) * HD_ + slot * 16 + hi * 8);

  f32x16 o0 = {}, o1 = {};              // O[q=crow(r,hi)][d = dt*32 + l31]
  float mr = -1e30f, lr = 0.f;          // stats for row q = l31 (lane-local)

  // staging: chunk c covers rows c*32 + w*8 + (lane>>3), cols (lane&7)*8
  const int srow = w * 8 + (lane >> 3);
  const int scol = (lane & 7) * 8;

  uint4 kreg[2], vreg[2];
#pragma unroll
  for (int c = 0; c < 2; ++c) {
    kreg[c] = *(const uint4*)(kp + (size_t)(c * 32 + srow) * HD_ + scol);
    vreg[c] = *(const uint4*)(vp + (size_t)(c * 32 + srow) * T_ + scol);
  }

  int buf = 0;
  for (int pass = 0; pass < npass; ++pass) {
    const int kv0 = pass * 64;
    // write staged 64-kv tile to LDS (padded rows; 2x b64 per uint4)
#pragma unroll
    for (int c = 0; c < 2; ++c) {
      const int row = c * 32 + srow;
      u16* kd = &kl[buf][row * 68 + scol];
      uint2 k0 = {kreg[c].x, kreg[c].y}, k1 = {kreg[c].z, kreg[c].w};
      *(uint2*)kd = k0;
      *(uint2*)(kd + 4) = k1;
      u16* vd = &vl[buf][row * 68 + scol];
      uint2 v0 = {vreg[c].x, vreg[c].y}, v1 = {vreg[c].z, vreg[c].w};
      *(uint2*)vd = v0;
      *(uint2*)(vd + 4) = v1;
    }
    // issue next pass's global loads (latency hides under compute — T14)
    if (pass + 1 < npass) {
      const int kvn = kv0 + 64;
#pragma unroll
      for (int c = 0; c < 2; ++c) {
        kreg[c] = *(const uint4*)(kp + (size_t)(kvn + c * 32 + srow) * HD_ + scol);
        vreg[c] = *(const uint4*)(vp + (size_t)(c * 32 + srow) * T_ + kvn + scol);
      }
    }
    __syncthreads();

#pragma unroll
    for (int half = 0; half < 2; ++half) {
      const int kvh = kv0 + half * 32;
      if (kvh > qbw + 31) break;        // wave-uniform causal skip
      const int base = half * 32;       // row/col offset within staged tile

      // S = K·Q^T (swapped): lane holds 16 kv values of q-row l31.
      f32x16 s = {};
      __builtin_amdgcn_s_setprio(1);
#pragma unroll
      for (int slot = 0; slot < 4; ++slot) {
        union { uint2 d[2]; bf16x8 v; } kf;
        const u16* kr = &kl[buf][(base + l31) * 68 + slot * 16 + hi * 8];
        kf.d[0] = *(const uint2*)kr;
        kf.d[1] = *(const uint2*)(kr + 4);
        s = __builtin_amdgcn_mfma_f32_32x32x16_bf16(kf.v, aq[slot], s, 0, 0, 0);
      }
      __builtin_amdgcn_s_setprio(0);

      // causal mask: kv = kvh + crow(r,hi), q = qbw + l31
      if (kvh + 31 > qbw) {
        const int qq = qbw + l31;
#pragma unroll
        for (int r = 0; r < 16; ++r) {
          const int kv = kvh + (r & 3) + 8 * (r >> 2) + 4 * hi;
          if (kv > qq) s[r] = -1e30f;
        }
      }

      // row max: in-lane tree + partner half
      float t[8];
#pragma unroll
      for (int r = 0; r < 8; ++r) t[r] = fmaxf(s[r], s[r + 8]);
#pragma unroll
      for (int r = 0; r < 4; ++r) t[r] = fmaxf(t[r], t[r + 4]);
      float pm = fmaxf(fmaxf(t[0], t[1]), fmaxf(t[2], t[3]));
      pm = fmaxf(pm, __shfl_xor(pm, 32));

      // deferred rescale (T13)
      if (__any(pm > mr + 8.f)) {
        const float mn = fmaxf(mr, pm);
        const float al = exp2f(mr - mn);
        mr = mn;
        lr *= al;
#pragma unroll
        for (int r = 0; r < 16; ++r) {
          const float ab = __shfl(al, ((r & 3) + 8 * (r >> 2) + 4 * hi) + (lane & 32));
          o0[r] *= ab;
          o1[r] *= ab;
        }
      }

      // P = exp2(S - mr) (in place), row sum
      float rs = 0.f;
#pragma unroll
      for (int r = 0; r < 16; ++r) {
        s[r] = exp2f(s[r] - mr);
        rs += s[r];
      }
      rs += __shfl_xor(rs, 32);
      lr += rs;

      // pack P to bf16 pairs; redistribute to PV A-fragments in-register.
      unsigned cw[8];
#pragma unroll
      for (int i = 0; i < 8; ++i) {
        union { __bf16 hh[2]; unsigned u; } pk;
        pk.hh[0] = (__bf16)s[2 * i];
        pk.hh[1] = (__bf16)s[2 * i + 1];
        cw[i] = pk.u;
      }
      const unsigned r0 = __shfl_xor(H ? cw[0] : cw[2], 32);
      const unsigned r1 = __shfl_xor(H ? cw[1] : cw[3], 32);
      const unsigned r2 = __shfl_xor(H ? cw[4] : cw[6], 32);
      const unsigned r3 = __shfl_xor(H ? cw[5] : cw[7], 32);
      union PU { unsigned u[4]; bf16x8 v; } pa0, pa1;
      pa0.u[0] = H ? r0 : cw[0];
      pa0.u[1] = H ? r1 : cw[1];
      pa0.u[2] = H ? cw[2] : r0;
      pa0.u[3] = H ? cw[3] : r1;
      pa1.u[0] = H ? r2 : cw[4];
      pa1.u[1] = H ? r3 : cw[5];
      pa1.u[2] = H ? cw[6] : r2;
      pa1.u[3] = H ? cw[7] : r3;

      // O += P·V : B-frags from vl rows d = dt*32 + l31, k-cols base + ks*16 + hi*8
      __builtin_amdgcn_s_setprio(1);
      {
        union { uint2 d[2]; bf16x8 v; } vf;
        const u16* vr0 = &vl[buf][l31 * 68 + base + hi * 8];
        vf.d[0] = *(const uint2*)vr0;
        vf.d[1] = *(const uint2*)(vr0 + 4);
        o0 = __builtin_amdgcn_mfma_f32_32x32x16_bf16(pa0.v, vf.v, o0, 0, 0, 0);
        vf.d[0] = *(const uint2*)(vr0 + 16);
        vf.d[1] = *(const uint2*)(vr0 + 20);
        o0 = __builtin_amdgcn_mfma_f32_32x32x16_bf16(pa1.v, vf.v, o0, 0, 0, 0);
        const u16* vr1 = &vl[buf][(32 + l31) * 68 + base + hi * 8];
        vf.d[0] = *(const uint2*)vr1;
        vf.d[1] = *(const uint2*)(vr1 + 4);
        o1 = __builtin_amdgcn_mfma_f32_32x32x16_bf16(pa0.v, vf.v, o1, 0, 0, 0);
        vf.d[0] = *(const uint2*)(vr1 + 16);
        vf.d[1] = *(const uint2*)(vr1 + 20);
        o1 = __builtin_amdgcn_mfma_f32_32x32x16_bf16(pa1.v, vf.v, o1, 0, 0, 0);
      }
      __builtin_amdgcn_s_setprio(0);
    }
    buf ^= 1;
  }

  // normalize + write: O row q=crow(r,hi) needs 1/lr from lane q (|32 half)
  const float il = 1.f / lr;
#pragma unroll
  for (int r = 0; r < 16; ++r) {
    const int cr = (r & 3) + 8 * (r >> 2) + 4 * hi;
    const float li = __shfl(il, cr + (lane & 32));
    const size_t row = (size_t)(qbw + cr) * E_;
    yb[row + l31] = tobf(o0[r] * li);
    yb[row + 32 + l31] = tobf(o1[r] * li);
  }
}

// ---------------- launch ----------------

extern "C" void kernel_launch(void* const* d_in, const int* in_sizes, int n_in,
                              void* d_out, int out_size, void* d_ws, size_t ws_size,
                              hipStream_t stream) {
  const float* x  = (const float*)d_in[0];
  const float* Wa = (const float*)d_in[1];
  const float* ba = (const float*)d_in[2];
  const float* Wp = (const float*)d_in[3];
  const float* bp = (const float*)d_in[4];
  float* out = (float*)d_out;

  u16* ws   = (u16*)d_ws;
  u16* xb   = ws;                                  // 8M  (x bf16; later y bf16)
  u16* waT  = xb  + (size_t)8 * 1024 * 1024;       // 3M  (W_attn^T bf16)
  u16* wpT  = waT + (size_t)3 * 1024 * 1024;       // 1M  (W_proj^T bf16)
  u16* qws  = wpT + (size_t)1024 * 1024;           // 8M  q [B,H,T,HD]
  u16* kws  = qws + (size_t)8 * 1024 * 1024;       // 8M  k [B,H,T,HD]
  u16* vtws = kws + (size_t)8 * 1024 * 1024;       // 8M  v^T [B,H,HD,T]
  u16* yws  = xb;                                  // alias

  cvt_bf16_kernel<<<dim3(8192), dim3(256), 0, stream>>>(x, xb, 8 * 1024 * 1024);
  transpose_cvt_kernel<<<dim3(96, 32), dim3(32, 8), 0, stream>>>(Wa, waT, 1024, 3072);
  transpose_cvt_kernel<<<dim3(32, 32), dim3(32, 8), 0, stream>>>(Wp, wpT, 1024, 1024);

  gemm_kernel<0><<<dim3(64, 12), dim3(512), 0, stream>>>(xb, waT, ba, qws, kws, vtws, nullptr);
  attn_kernel<<<dim3(1024), dim3(256), 0, stream>>>(qws, kws, vtws, yws);
  gemm_kernel<1><<<dim3(64, 4), dim3(512), 0, stream>>>(yws, wpT, bp, nullptr, nullptr, nullptr, out);
}

// Round 13
// 175.116 us; speedup vs baseline: 2.1957x; 1.0138x over previous
//
#include <hip/hip_runtime.h>
#include <hip/hip_bf16.h>
#include <stdint.h>

// Fused causal self-attention block: qkv GEMM -> flash attention -> proj GEMM.
// B=4 T=2048 E=1024 H=16 HD=64. All matmuls bf16 MFMA, fp32 accumulate.
// GEMMs: 128x256 tile, BK=64, 8 waves, 3-buf pipeline, ONE barrier + ONE
// counted vmcnt(6) per K-tile (32 MFMA between barriers), slot-XOR LDS
// swizzle both-sides (T2/T21), setprio (T5), coalesced V^T epilogue via LDS.
// Attention: 32x32 swapped-QK (mfma(K,Q)) with fully in-register softmax;
// cross-32 exchanges via v_permlane32_swap (T12, no ds_bpermute);
// 64-kv staging passes; CU-balanced LPT tile map.

#define B_  4
#define T_  2048
#define E_  1024
#define H_  16
#define HD_ 64

typedef unsigned short u16;
typedef __bf16 bf16x8 __attribute__((ext_vector_type(8)));
typedef float f32x4 __attribute__((ext_vector_type(4)));
typedef float f32x16 __attribute__((ext_vector_type(16)));
typedef unsigned uint2v __attribute__((ext_vector_type(2)));

struct alignas(8) us4 { u16 x, y, z, w; };

// native bf16 convert (compiler emits v_cvt_pk_bf16_f32; RNE)
__device__ __forceinline__ u16 tobf(float f) {
  union { __bf16 h; u16 u; } c;
  c.h = (__bf16)f;
  return c.u;
}

__device__ __forceinline__ void gload_lds16(const void* g, void* l) {
  // global -> LDS direct, 16B/lane (wave-uniform LDS base + lane*16).
  auto gp = reinterpret_cast<const __attribute__((address_space(1))) uint32_t*>(
      reinterpret_cast<uintptr_t>(g));
  auto lp = reinterpret_cast<__attribute__((address_space(3))) uint32_t*>(
      reinterpret_cast<uintptr_t>(l));
  __builtin_amdgcn_global_load_lds(gp, lp, 16, 0, 0);
}

__device__ __forceinline__ bf16x8 ld_frag(const u16* p) {
  return *reinterpret_cast<const bf16x8*>(p);
}

// cross-32 reduce via v_permlane32_swap (VALU; replaces ds_bpermute shfl_xor)
__device__ __forceinline__ float xmax32(float x) {
  uint2v r = __builtin_amdgcn_permlane32_swap(__float_as_uint(x), __float_as_uint(x), false, false);
  return fmaxf(__uint_as_float(r.x), __uint_as_float(r.y));
}
__device__ __forceinline__ float xsum32(float x) {
  uint2v r = __builtin_amdgcn_permlane32_swap(__float_as_uint(x), __float_as_uint(x), false, false);
  return __uint_as_float(r.x) + __uint_as_float(r.y);
}

// raw barrier + compiler memory fence (NOT __syncthreads: that drains vmcnt(0)
// and kills the counted-vmcnt pipeline)
#define BARRIER() do { __builtin_amdgcn_s_barrier(); asm volatile("" ::: "memory"); } while (0)

// ---------------- conversion kernels ----------------

__global__ void cvt_bf16_kernel(const float* __restrict__ in, u16* __restrict__ out, int n) {
  int i = (blockIdx.x * blockDim.x + threadIdx.x) * 4;
  if (i >= n) return;
  float4 v = *reinterpret_cast<const float4*>(in + i);
  us4 o = { tobf(v.x), tobf(v.y), tobf(v.z), tobf(v.w) };
  *reinterpret_cast<us4*>(out + i) = o;
}

// in: [K][N] f32 row-major -> out: [N][K] bf16 (B^T layout for GEMM)
__global__ void transpose_cvt_kernel(const float* __restrict__ in, u16* __restrict__ out,
                                     int K, int N) {
  __shared__ u16 tile[32][33];
  int n0 = blockIdx.x * 32, k0 = blockIdx.y * 32;
  int tx = threadIdx.x, ty = threadIdx.y;  // (32,8)
#pragma unroll
  for (int i = 0; i < 32; i += 8)
    tile[ty + i][tx] = tobf(in[(size_t)(k0 + ty + i) * N + n0 + tx]);
  __syncthreads();
#pragma unroll
  for (int i = 0; i < 32; i += 8)
    out[(size_t)(n0 + ty + i) * K + k0 + tx] = tile[tx][ty + i];
}

// ---------------- GEMM: 128x256, BK=64, 8 waves, 3-buf, 1 barrier/K-tile ---

template <int MODE>
__launch_bounds__(512, 2)
__global__ void gemm_kernel(const u16* __restrict__ A, const u16* __restrict__ Bt,
                            const float* __restrict__ bias,
                            u16* __restrict__ qws, u16* __restrict__ kws,
                            u16* __restrict__ vtws, float* __restrict__ out) {
  constexpr int K = 1024, NT = 16;     // 16 K-tiles of 64
  __shared__ u16 Asm[3 * 8192];        // 3 bufs x 128x64  (48KB)
  __shared__ u16 Bsm[3 * 16384];       // 3 bufs x 256x64  (96KB)
  const int tid = threadIdx.x;
  const int wid = tid >> 6, lane = tid & 63;
  const int wm = wid >> 2, wn = wid & 3;     // 2M x 4N waves; 64x64 out/wave
  const int row0 = blockIdx.x * 128, col0 = blockIdx.y * 256;

  const int sgrow = wid * 8 + (lane >> 3);
  const int sgslot = (lane & 7) ^ (lane >> 3);
  const int lrow = lane & 15, lks = lane >> 4, r7 = lrow & 7;
  const int ca0 = ((lks) ^ r7) * 8;          // kk=0 col offset (u16)
  const int ca1 = ((4 + lks) ^ r7) * 8;      // kk=1
  const int bhalf = (wn >> 1) * 8192 + (wn & 1) * 4096;

#define STG_A(sb, kt, j)                                                        \
  gload_lds16(A + (size_t)(row0 + (j) * 64 + sgrow) * K + (kt) * 64 + sgslot * 8, \
              &Asm[(sb) * 8192 + (j) * 4096 + wid * 512])
#define STG_B(sb, kt, h, j)                                                     \
  gload_lds16(Bt + (size_t)(col0 + (h) * 128 + (j) * 64 + sgrow) * K + (kt) * 64 + sgslot * 8, \
              &Bsm[(sb) * 16384 + (h) * 8192 + (j) * 4096 + wid * 512])
#define RDA(mi, cc) ld_frag(&Asm[rb * 8192 + (wm * 64 + (mi) * 16 + lrow) * 64 + (cc)])
#define RDB(ni, cc) ld_frag(&Bsm[rb * 16384 + bhalf + ((ni) * 16 + lrow) * 64 + (cc)])

  f32x4 acc[4][4] = {};

  // prologue: stage K-tiles 0 (buf 0) and 1 (buf 1), 6 loads each, in order
  STG_A(0, 0, 0); STG_A(0, 0, 1);
  STG_B(0, 0, 0, 0); STG_B(0, 0, 0, 1); STG_B(0, 0, 1, 0); STG_B(0, 0, 1, 1);
  STG_A(1, 1, 0); STG_A(1, 1, 1);
  STG_B(1, 1, 0, 0); STG_B(1, 1, 0, 1); STG_B(1, 1, 1, 0); STG_B(1, 1, 1, 1);
  asm volatile("s_waitcnt vmcnt(6)" ::: "memory");  // tile 0's 6 landed
  BARRIER();

  for (int t = 0; t < NT; ++t) {
    const int rb = t % 3;
    const int sb = (t + 2) % 3;       // buffer of tile t+2 (freed at end of t-1)
    const bool hs = (t + 2) < NT;
    const int kt = t + 2;
    bf16x8 af[4], bf[4];

    // kk=0 frags + stage A(t+2)
    af[0] = RDA(0, ca0); af[1] = RDA(1, ca0); af[2] = RDA(2, ca0); af[3] = RDA(3, ca0);
    bf[0] = RDB(0, ca0); bf[1] = RDB(1, ca0); bf[2] = RDB(2, ca0); bf[3] = RDB(3, ca0);
    if (hs) { STG_A(sb, kt, 0); STG_A(sb, kt, 1); }
    __builtin_amdgcn_s_setprio(1);
#pragma unroll
    for (int mi = 0; mi < 4; ++mi)
#pragma unroll
      for (int ni = 0; ni < 4; ++ni)
        acc[mi][ni] = __builtin_amdgcn_mfma_f32_16x16x32_bf16(af[mi], bf[ni], acc[mi][ni], 0, 0, 0);
    __builtin_amdgcn_s_setprio(0);

    // kk=1 frags + stage B(t+2)
    af[0] = RDA(0, ca1); af[1] = RDA(1, ca1); af[2] = RDA(2, ca1); af[3] = RDA(3, ca1);
    bf[0] = RDB(0, ca1); bf[1] = RDB(1, ca1); bf[2] = RDB(2, ca1); bf[3] = RDB(3, ca1);
    if (hs) { STG_B(sb, kt, 0, 0); STG_B(sb, kt, 0, 1); STG_B(sb, kt, 1, 0); STG_B(sb, kt, 1, 1); }
    __builtin_amdgcn_s_setprio(1);
#pragma unroll
    for (int mi = 0; mi < 4; ++mi)
#pragma unroll
      for (int ni = 0; ni < 4; ++ni)
        acc[mi][ni] = __builtin_amdgcn_mfma_f32_16x16x32_bf16(af[mi], bf[ni], acc[mi][ni], 0, 0, 0);
    __builtin_amdgcn_s_setprio(0);

    // drain tile t+1's stages (issued during t-1); leave this tile's 6 in flight
    if (hs) asm volatile("s_waitcnt vmcnt(6)" ::: "memory");
    else    asm volatile("s_waitcnt vmcnt(0)" ::: "memory");
    BARRIER();  // publishes stages for t+1 AND fences re-staging of rb(t) by t+1
  }
#undef STG_A
#undef STG_B
#undef RDA
#undef RDB

  // C/D layout: col = lane&15, row = (lane>>4)*4 + reg
  if constexpr (MODE == 0) {
    const int part = (col0 + wn * 64) >> 10;    // wave-uniform: 0=q 1=k 2=v
    if (part < 2) {
#pragma unroll
      for (int mi = 0; mi < 4; ++mi) {
#pragma unroll
        for (int ni = 0; ni < 4; ++ni) {
          const int gr0 = row0 + wm * 64 + mi * 16 + (lane >> 4) * 4;
          const int gc = col0 + wn * 64 + ni * 16 + (lane & 15);
          const float bv = bias[gc];
          const int e = gc & 1023;
          const int h = e >> 6, d = e & 63;
#pragma unroll
          for (int r = 0; r < 4; ++r) {
            const int m = gr0 + r;
            const int b = m >> 11, tt = m & 2047;
            const float val = acc[mi][ni][r] + bv;
            const size_t bh = (size_t)(b * H_ + h);
            if (part == 0)
              // fold 1/sqrt(64) * log2(e): softmax done in exp2 domain
              qws[(bh * T_ + tt) * HD_ + d] = tobf(val * 0.1803368801f);
            else
              kws[(bh * T_ + tt) * HD_ + d] = tobf(val);
          }
        }
      }
    } else {
      // V: transpose via per-wave LDS scratch stored [d_local][t_local]
      // (rows padded to 72 u16), then 8 coalesced b128 stores along T.
      u16* vt_l = &Bsm[wid * 4608];
#pragma unroll
      for (int mi = 0; mi < 4; ++mi)
#pragma unroll
        for (int ni = 0; ni < 4; ++ni) {
          const float bv = bias[col0 + wn * 64 + ni * 16 + (lane & 15)];
#pragma unroll
          for (int r = 0; r < 4; ++r)
            vt_l[(ni * 16 + (lane & 15)) * 72 + mi * 16 + (lane >> 4) * 4 + r] =
                tobf(acc[mi][ni][r] + bv);
        }
      const int e0 = col0 + wn * 64 - 2048;   // multiple of 64 -> one full head
      const int h = e0 >> 6;
      const int m0 = row0 + wm * 64;
      const int b = m0 >> 11, tbase = m0 & 2047;
      u16* vbase = vtws + (size_t)(b * H_ + h) * HD_ * T_;
#pragma unroll
      for (int it = 0; it < 8; ++it) {
        const int d = it * 8 + (lane >> 3);
        const uint4 vv = *reinterpret_cast<const uint4*>(&vt_l[d * 72 + (lane & 7) * 8]);
        *reinterpret_cast<uint4*>(&vbase[(size_t)d * T_ + tbase + (lane & 7) * 8]) = vv;
      }
    }
  } else {
#pragma unroll
    for (int mi = 0; mi < 4; ++mi) {
#pragma unroll
      for (int ni = 0; ni < 4; ++ni) {
        const int gr0 = row0 + wm * 64 + mi * 16 + (lane >> 4) * 4;
        const int gc = col0 + wn * 64 + ni * 16 + (lane & 15);
        const float bv = bias[gc];
#pragma unroll
        for (int r = 0; r < 4; ++r)
          out[(size_t)(gr0 + r) * E_ + gc] = acc[mi][ni][r] + bv;
      }
    }
  }
}

// ---------------- flash attention (32x32 swapped-QK, in-register softmax) ---
// grid = 1024 blocks x 256 threads (4 waves). CU-balanced LPT map: with
// s=bid>>8, a=(bid>>6)&3, j = {15-a, 8+a, 7-a, a}[s] -> every CU's 4 blocks
// sum to 30 work units; long tiles dispatch first; bh=bid&63 keeps heads
// XCD-pinned. Wave owns 32 q rows. QK^T swapped (A=K, B=Q, 32x32x16): lane
// holds a full q-row -> softmax in-lane + one permlane32_swap (VALU — no
// ds_bpermute). P redistributed to PV A-frags via 4 permlane32_swap.
// K/V staged at 64-kv granularity, reg-staged (T14), padded rows, dbuf.
// Defer-max (T13); setprio (T5); max3 reduction tree (T17).

__launch_bounds__(256, 4)
__global__ void attn_kernel(const u16* __restrict__ q, const u16* __restrict__ k,
                            const u16* __restrict__ vt, u16* __restrict__ y) {
  __shared__ u16 kl[2][64 * 68];   // K: 64 kv rows x 64 hd, rows padded to 136B
  __shared__ u16 vl[2][64 * 68];   // V^T: 64 d rows x 64 kv, rows padded to 136B
  const int tid = threadIdx.x, w = tid >> 6, lane = tid & 63;
  const int l31 = lane & 31, hi = lane >> 5;
  const int bid = blockIdx.x;
  const int s4 = bid >> 8, a = (bid >> 6) & 3;
  const int j = (s4 == 0) ? (15 - a) : (s4 == 1) ? (8 + a) : (s4 == 2) ? (7 - a) : a;
  const int bh = bid & 63;
  const u16* qp = q + (size_t)bh * T_ * HD_;
  const u16* kp = k + (size_t)bh * T_ * HD_;
  const u16* vp = vt + (size_t)bh * HD_ * T_;
  const int b = bh >> 4, h = bh & 15;
  u16* yb = y + (size_t)b * T_ * E_ + h * HD_;

  const int t0 = j * 128;
  const int qbw = t0 + w * 32;          // wave's first q row
  const int npass = (t0 + 128) >> 6;    // 64-kv staging passes

  // Q fragments (B-operand): lane holds Q[qbw + l31][slot*16 + hi*8 + e]
  bf16x8 aq[4];
#pragma unroll
  for (int slot = 0; slot < 4; ++slot)
    aq[slot] = ld_frag(qp + (size_t)(qbw + l31) * HD_ + slot * 16 + hi * 8);

  f32x16 o0 = {}, o1 = {};              // O[q=crow(r,hi)][d = dt*32 + l31]
  float mr = -1e30f, lr = 0.f;          // stats for row q = l31 (lane-local)

  // staging: chunk c covers rows c*32 + w*8 + (lane>>3), cols (lane&7)*8
  const int srow = w * 8 + (lane >> 3);
  const int scol = (lane & 7) * 8;

  uint4 kreg[2], vreg[2];
#pragma unroll
  for (int c = 0; c < 2; ++c) {
    kreg[c] = *(const uint4*)(kp + (size_t)(c * 32 + srow) * HD_ + scol);
    vreg[c] = *(const uint4*)(vp + (size_t)(c * 32 + srow) * T_ + scol);
  }

  int buf = 0;
  for (int pass = 0; pass < npass; ++pass) {
    const int kv0 = pass * 64;
    // write staged 64-kv tile to LDS (padded rows; 2x b64 per uint4)
#pragma unroll
    for (int c = 0; c < 2; ++c) {
      const int row = c * 32 + srow;
      u16* kd = &kl[buf][row * 68 + scol];
      uint2 k0 = {kreg[c].x, kreg[c].y}, k1 = {kreg[c].z, kreg[c].w};
      *(uint2*)kd = k0;
      *(uint2*)(kd + 4) = k1;
      u16* vd = &vl[buf][row * 68 + scol];
      uint2 v0 = {vreg[c].x, vreg[c].y}, v1 = {vreg[c].z, vreg[c].w};
      *(uint2*)vd = v0;
      *(uint2*)(vd + 4) = v1;
    }
    // issue next pass's global loads (latency hides under compute — T14)
    if (pass + 1 < npass) {
      const int kvn = kv0 + 64;
#pragma unroll
      for (int c = 0; c < 2; ++c) {
        kreg[c] = *(const uint4*)(kp + (size_t)(kvn + c * 32 + srow) * HD_ + scol);
        vreg[c] = *(const uint4*)(vp + (size_t)(c * 32 + srow) * T_ + kvn + scol);
      }
    }
    __syncthreads();

#pragma unroll
    for (int half = 0; half < 2; ++half) {
      const int kvh = kv0 + half * 32;
      if (kvh > qbw + 31) break;        // wave-uniform causal skip
      const int base = half * 32;       // row/col offset within staged tile

      // S = K·Q^T (swapped): lane holds 16 kv values of q-row l31.
      f32x16 s = {};
      __builtin_amdgcn_s_setprio(1);
#pragma unroll
      for (int slot = 0; slot < 4; ++slot) {
        union { uint2 d[2]; bf16x8 v; } kf;
        const u16* kr = &kl[buf][(base + l31) * 68 + slot * 16 + hi * 8];
        kf.d[0] = *(const uint2*)kr;
        kf.d[1] = *(const uint2*)(kr + 4);
        s = __builtin_amdgcn_mfma_f32_32x32x16_bf16(kf.v, aq[slot], s, 0, 0, 0);
      }
      __builtin_amdgcn_s_setprio(0);

      // causal mask: kv = kvh + crow(r,hi), q = qbw + l31
      if (kvh + 31 > qbw) {
        const int qq = qbw + l31;
#pragma unroll
        for (int r = 0; r < 16; ++r) {
          const int kv = kvh + (r & 3) + 8 * (r >> 2) + 4 * hi;
          if (kv > qq) s[r] = -1e30f;
        }
      }

      // row max: max3-friendly tree (T17) + cross-32 swap
      const float t0m = fmaxf(fmaxf(s[0], s[1]), s[2]);
      const float t1m = fmaxf(fmaxf(s[3], s[4]), s[5]);
      const float t2m = fmaxf(fmaxf(s[6], s[7]), s[8]);
      const float t3m = fmaxf(fmaxf(s[9], s[10]), s[11]);
      const float t4m = fmaxf(fmaxf(s[12], s[13]), s[14]);
      float pm = fmaxf(fmaxf(fmaxf(t0m, t1m), t2m),
                       fmaxf(fmaxf(t3m, t4m), s[15]));
      pm = xmax32(pm);

      // deferred rescale (T13)
      if (__any(pm > mr + 8.f)) {
        const float mn = fmaxf(mr, pm);
        const float al = exp2f(mr - mn);
        mr = mn;
        lr *= al;
#pragma unroll
        for (int r = 0; r < 16; ++r) {
          const float ab = __shfl(al, ((r & 3) + 8 * (r >> 2) + 4 * hi) + (lane & 32));
          o0[r] *= ab;
          o1[r] *= ab;
        }
      }

      // P = exp2(S - mr) (in place), row sum
      float rs = 0.f;
#pragma unroll
      for (int r = 0; r < 16; ++r) {
        s[r] = exp2f(s[r] - mr);
        rs += s[r];
      }
      lr += xsum32(rs);

      // pack P to bf16 pairs; redistribute to PV A-frags via permlane32_swap:
      // (u[0],u[2]) = swap(cw0, cw2): lo lane gets (own cw0, partner cw0),
      // hi lane gets (partner cw2, own cw2) — exactly the A-frag layout.
      unsigned cw[8];
#pragma unroll
      for (int i = 0; i < 8; ++i) {
        union { __bf16 hh[2]; unsigned u; } pk;
        pk.hh[0] = (__bf16)s[2 * i];
        pk.hh[1] = (__bf16)s[2 * i + 1];
        cw[i] = pk.u;
      }
      union PU { unsigned u[4]; bf16x8 v; } pa0, pa1;
      {
        const uint2v q0 = __builtin_amdgcn_permlane32_swap(cw[0], cw[2], false, false);
        const uint2v q1 = __builtin_amdgcn_permlane32_swap(cw[1], cw[3], false, false);
        const uint2v q2 = __builtin_amdgcn_permlane32_swap(cw[4], cw[6], false, false);
        const uint2v q3 = __builtin_amdgcn_permlane32_swap(cw[5], cw[7], false, false);
        pa0.u[0] = q0.x; pa0.u[2] = q0.y;
        pa0.u[1] = q1.x; pa0.u[3] = q1.y;
        pa1.u[0] = q2.x; pa1.u[2] = q2.y;
        pa1.u[1] = q3.x; pa1.u[3] = q3.y;
      }

      // O += P·V : B-frags from vl rows d = dt*32 + l31, k-cols base + ks*16 + hi*8
      __builtin_amdgcn_s_setprio(1);
      {
        union { uint2 d[2]; bf16x8 v; } vf;
        const u16* vr0 = &vl[buf][l31 * 68 + base + hi * 8];
        vf.d[0] = *(const uint2*)vr0;
        vf.d[1] = *(const uint2*)(vr0 + 4);
        o0 = __builtin_amdgcn_mfma_f32_32x32x16_bf16(pa0.v, vf.v, o0, 0, 0, 0);
        vf.d[0] = *(const uint2*)(vr0 + 16);
        vf.d[1] = *(const uint2*)(vr0 + 20);
        o0 = __builtin_amdgcn_mfma_f32_32x32x16_bf16(pa1.v, vf.v, o0, 0, 0, 0);
        const u16* vr1 = &vl[buf][(32 + l31) * 68 + base + hi * 8];
        vf.d[0] = *(const uint2*)vr1;
        vf.d[1] = *(const uint2*)(vr1 + 4);
        o1 = __builtin_amdgcn_mfma_f32_32x32x16_bf16(pa0.v, vf.v, o1, 0, 0, 0);
        vf.d[0] = *(const uint2*)(vr1 + 16);
        vf.d[1] = *(const uint2*)(vr1 + 20);
        o1 = __builtin_amdgcn_mfma_f32_32x32x16_bf16(pa1.v, vf.v, o1, 0, 0, 0);
      }
      __builtin_amdgcn_s_setprio(0);
    }
    buf ^= 1;
  }

  // normalize + write: O row q=crow(r,hi) needs 1/lr from lane q (|32 half)
  const float il = 1.f / lr;
#pragma unroll
  for (int r = 0; r < 16; ++r) {
    const int cr = (r & 3) + 8 * (r >> 2) + 4 * hi;
    const float li = __shfl(il, cr + (lane & 32));
    const size_t row = (size_t)(qbw + cr) * E_;
    yb[row + l31] = tobf(o0[r] * li);
    yb[row + 32 + l31] = tobf(o1[r] * li);
  }
}

// ---------------- launch ----------------

extern "C" void kernel_launch(void* const* d_in, const int* in_sizes, int n_in,
                              void* d_out, int out_size, void* d_ws, size_t ws_size,
                              hipStream_t stream) {
  const float* x  = (const float*)d_in[0];
  const float* Wa = (const float*)d_in[1];
  const float* ba = (const float*)d_in[2];
  const float* Wp = (const float*)d_in[3];
  const float* bp = (const float*)d_in[4];
  float* out = (float*)d_out;

  u16* ws   = (u16*)d_ws;
  u16* xb   = ws;                                  // 8M  (x bf16; later y bf16)
  u16* waT  = xb  + (size_t)8 * 1024 * 1024;       // 3M  (W_attn^T bf16)
  u16* wpT  = waT + (size_t)3 * 1024 * 1024;       // 1M  (W_proj^T bf16)
  u16* qws  = wpT + (size_t)1024 * 1024;           // 8M  q [B,H,T,HD]
  u16* kws  = qws + (size_t)8 * 1024 * 1024;       // 8M  k [B,H,T,HD]
  u16* vtws = kws + (size_t)8 * 1024 * 1024;       // 8M  v^T [B,H,HD,T]
  u16* yws  = xb;                                  // alias

  cvt_bf16_kernel<<<dim3(8192), dim3(256), 0, stream>>>(x, xb, 8 * 1024 * 1024);
  transpose_cvt_kernel<<<dim3(96, 32), dim3(32, 8), 0, stream>>>(Wa, waT, 1024, 3072);
  transpose_cvt_kernel<<<dim3(32, 32), dim3(32, 8), 0, stream>>>(Wp, wpT, 1024, 1024);

  gemm_kernel<0><<<dim3(64, 12), dim3(512), 0, stream>>>(xb, waT, ba, qws, kws, vtws, nullptr);
  attn_kernel<<<dim3(1024), dim3(256), 0, stream>>>(qws, kws, vtws, yws);
  gemm_kernel<1><<<dim3(64, 4), dim3(512), 0, stream>>>(yws, wpT, bp, nullptr, nullptr, nullptr, out);
}